// Round 5
// baseline (794.558 us; speedup 1.0000x reference)
//
#include <hip/hip_runtime.h>
#include <hip/hip_bf16.h>
#include <math.h>

typedef __hip_bfloat16 bf16;
typedef __attribute__((ext_vector_type(8))) short bf16x8;
typedef __attribute__((ext_vector_type(4))) float f32x4;
typedef __attribute__((ext_vector_type(16))) float f32x16;

static constexpr int DD = 1024;    // D
static constexpr int BB = 4;       // batch
static constexpr int SS = 4096;    // seq
static constexpr int FD = 4096;    // 4D
static constexpr int GDIM = 2048;  // 2D
static constexpr long SD = (long)SS * DD;   // per-batch x elements (4M)
static constexpr long SD4 = 4 * SD;         // per-batch ctx elements

// ---------------- async global->LDS (16B per lane) ----------------
__device__ __forceinline__ void gl2lds16(const bf16* g, bf16* l) {
    __builtin_amdgcn_global_load_lds(
        (const __attribute__((address_space(1))) void*)g,
        (__attribute__((address_space(3))) void*)l, 16, 0, 0);
}

// ---------------- branchless exact-erf GELU (A&S 7.1.26, |eps|<=1.5e-7) -----
__device__ __forceinline__ float gelu_exact(float v) {
    const float ax = fabsf(v) * 0.70710678118654752f;  // |v|/sqrt(2)
    const float t = 1.0f / (1.0f + 0.3275911f * ax);
    const float poly = t * (0.254829592f + t * (-0.284496736f +
                       t * (1.421413741f + t * (-1.453152027f + t * 1.061405429f))));
    const float er = 1.0f - poly * __expf(-ax * ax);
    const float erfv = v < 0.f ? -er : er;
    return 0.5f * v * (1.0f + erfv);
}

// ================= 256x256 GEMM, 32x32x16 MFMA, 2 barriers/K-tile ==========
// C[M,N] = A[M,K] * BT[N,K]^T, bf16 in, z-batched via strides.
// BM=BN=256, BK=64, 512 threads = 8 waves (2Mx4N), per-wave output 128x64.
// LDS 128 KiB: A/B each [2 buf][2 kslice][256 rows][32 k] bf16.
// Per K-tile: 2 half-tiles (K32). Per half: 12 ds_read_b128 (B then A),
// then 2 groups of 8 v_mfma_f32_32x32x16_bf16 (h = k-16-subslice), stage
// loads interleaved exactly as round-2 (best measured). Counted vmcnt:
// vmcnt(6) mid-tile, vmcnt(4) end-of-tile; never 0 in steady state.
// LDS swizzle (verified 0-conflict): 16B chunk c at row r holds global
// chunk c ^ ((r>>1)&3); applied on per-lane GLOBAL source (linear gl2lds
// dest) and on ds_read chunk.
// 32x32x16 lane maps: A/B: row/col = l&31, k = (l>>5)*8+e within 16-slice;
// C/D: col = l&31, row = (r&3)+8*(r>>2)+4*(l>>5), r=0..15.
// EPI 0: +bias[row], bf16   EPI 1: +bias[col], gelu, bf16   EPI 2: +bias[col]+X, f32
template <int EPI>
__global__ __launch_bounds__(512, 2) void gemm256(
    const bf16* __restrict__ A, const bf16* __restrict__ BT, void* __restrict__ Cp,
    const float* __restrict__ bias, const float* __restrict__ Xadd,
    int M, int N, int K, long strA, long strBT, long strC)
{
    extern __shared__ bf16 lds[];  // 65536 elems: A [0,32768), B [32768,65536)
    const int tid = threadIdx.x;
    const int l = tid & 63, wv = tid >> 6;
    const int wr = wv >> 2, wc = wv & 3;

    // T1: bijective XCD swizzle over the per-z 2D grid
    int lin = blockIdx.y * gridDim.x + blockIdx.x;
    {
        const int nwg = gridDim.x * gridDim.y;
        const int qq = nwg >> 3, rr = nwg & 7;
        const int xcd = lin & 7, idx = lin >> 3;
        lin = (xcd < rr ? xcd * (qq + 1) : rr * (qq + 1) + (xcd - rr) * qq) + idx;
    }
    const long m0 = (long)(lin / gridDim.x) * 256;
    const long n0 = (long)(lin % gridDim.x) * 256;

    A += (long)blockIdx.z * strA;
    BT += (long)blockIdx.z * strBT;

    // staging: thread t covers row (t>>2) [+128 for 2nd inst], 16B chunk (t&3),
    // source pre-swizzled: global chunk = (t&3) ^ ((row>>1)&3)
    const int schunk = (tid & 3) ^ ((tid >> 3) & 3);
    const bf16* pa = A + (m0 + (tid >> 2)) * (long)K + schunk * 8;
    const bf16* pb = BT + (n0 + (tid >> 2)) * (long)K + schunk * 8;
    const long rowK = 128L * (long)K;
    const int stgOff = wv * 512;  // wave-uniform 1 KiB slot

    // 32x32 fragment lane decomposition
    const int r31 = l & 31, kh = l >> 5;

    f32x16 acc[4][2];
#pragma unroll
    for (int i = 0; i < 4; ++i)
#pragma unroll
        for (int j = 0; j < 2; ++j)
#pragma unroll
            for (int r = 0; r < 16; ++r) acc[i][j][r] = 0.f;

    const int NT = K >> 6;

    // ---- prologue: stage all 4 halves of tile 0 into buf0
    {
        bf16* dA0 = lds + stgOff;
        bf16* dA1 = lds + 8192 + stgOff;
        bf16* dB0 = lds + 32768 + stgOff;
        bf16* dB1 = lds + 40960 + stgOff;
        gl2lds16(pa, dA0);       gl2lds16(pa + rowK, dA0 + 4096);
        gl2lds16(pb, dB0);       gl2lds16(pb + rowK, dB0 + 4096);
        gl2lds16(pa + 32, dA1);  gl2lds16(pa + 32 + rowK, dA1 + 4096);
        gl2lds16(pb + 32, dB1);  gl2lds16(pb + 32 + rowK, dB1 + 4096);
        asm volatile("s_waitcnt vmcnt(4)" ::: "memory");  // s0 done, s1 (4) in flight
        __builtin_amdgcn_s_barrier();
    }

    for (int t = 0; t < NT; ++t) {
        const int buf = t & 1;
        const bool more = (t + 1) < NT;
        const long ko = (long)(t + 1) * 64;
        const bf16* As0 = lds + buf * 16384;
        const bf16* As1 = As0 + 8192;
        const bf16* Bs0 = lds + 32768 + buf * 16384;
        const bf16* Bs1 = Bs0 + 8192;
        bf16* nA0 = lds + (buf ^ 1) * 16384 + stgOff;
        bf16* nA1 = nA0 + 8192;
        bf16* nB0 = lds + 32768 + (buf ^ 1) * 16384 + stgOff;
        bf16* nB1 = nB0 + 8192;

        // ================= half 0 (kslice 0) =================
        {
            bf16x8 bq[2][2], af[4][2];
#pragma unroll
            for (int h = 0; h < 2; ++h)
#pragma unroll
                for (int j = 0; j < 2; ++j) {
                    const int br = wc * 64 + j * 32 + r31;
                    const int ch = (kh + 2 * h) ^ ((br >> 1) & 3);
                    bq[j][h] = *(const bf16x8*)(Bs0 + br * 32 + ch * 8);
                }
#pragma unroll
            for (int h = 0; h < 2; ++h)
#pragma unroll
                for (int i = 0; i < 4; ++i) {
                    const int ar = wr * 128 + i * 32 + r31;
                    const int ch = (kh + 2 * h) ^ ((ar >> 1) & 3);
                    af[i][h] = *(const bf16x8*)(As0 + ar * 32 + ch * 8);
                }
            if (more) {
                gl2lds16(pa + ko, nA0); gl2lds16(pa + ko + rowK, nA0 + 4096);   // S_A0
                gl2lds16(pb + ko, nB0); gl2lds16(pb + ko + rowK, nB0 + 4096);   // S_B0
            }
            __builtin_amdgcn_s_setprio(1);
#pragma unroll
            for (int i = 0; i < 4; ++i)
#pragma unroll
                for (int j = 0; j < 2; ++j)
                    acc[i][j] = __builtin_amdgcn_mfma_f32_32x32x16_bf16(af[i][0], bq[j][0], acc[i][j], 0, 0, 0);
            __builtin_amdgcn_s_setprio(0);
            if (more) { gl2lds16(pa + ko + 32, nA1); gl2lds16(pa + ko + 32 + rowK, nA1 + 4096); }  // S_A1
            __builtin_amdgcn_s_setprio(1);
#pragma unroll
            for (int i = 0; i < 4; ++i)
#pragma unroll
                for (int j = 0; j < 2; ++j)
                    acc[i][j] = __builtin_amdgcn_mfma_f32_32x32x16_bf16(af[i][1], bq[j][1], acc[i][j], 0, 0, 0);
            __builtin_amdgcn_s_setprio(0);
        }
        // publish s1(t): retire the 4 oldest (s1 stages from tile t-1 / prologue)
        if (more) asm volatile("s_waitcnt vmcnt(6)" ::: "memory");
        else      asm volatile("s_waitcnt vmcnt(0)" ::: "memory");
        __builtin_amdgcn_s_barrier();

        // ================= half 1 (kslice 1) =================
        {
            bf16x8 bq[2][2], af[4][2];
#pragma unroll
            for (int h = 0; h < 2; ++h)
#pragma unroll
                for (int j = 0; j < 2; ++j) {
                    const int br = wc * 64 + j * 32 + r31;
                    const int ch = (kh + 2 * h) ^ ((br >> 1) & 3);
                    bq[j][h] = *(const bf16x8*)(Bs1 + br * 32 + ch * 8);
                }
#pragma unroll
            for (int h = 0; h < 2; ++h)
#pragma unroll
                for (int i = 0; i < 4; ++i) {
                    const int ar = wr * 128 + i * 32 + r31;
                    const int ch = (kh + 2 * h) ^ ((ar >> 1) & 3);
                    af[i][h] = *(const bf16x8*)(As1 + ar * 32 + ch * 8);
                }
            if (more) { gl2lds16(pb + ko + 32, nB1); gl2lds16(pb + ko + 32 + rowK, nB1 + 4096); }  // S_B1
            __builtin_amdgcn_s_setprio(1);
#pragma unroll
            for (int i = 0; i < 4; ++i)
#pragma unroll
                for (int j = 0; j < 2; ++j)
                    acc[i][j] = __builtin_amdgcn_mfma_f32_32x32x16_bf16(af[i][0], bq[j][0], acc[i][j], 0, 0, 0);
            __builtin_amdgcn_s_setprio(0);
            __builtin_amdgcn_s_setprio(1);
#pragma unroll
            for (int i = 0; i < 4; ++i)
#pragma unroll
                for (int j = 0; j < 2; ++j)
                    acc[i][j] = __builtin_amdgcn_mfma_f32_32x32x16_bf16(af[i][1], bq[j][1], acc[i][j], 0, 0, 0);
            __builtin_amdgcn_s_setprio(0);
        }
        // publish s0(t+1): retire S_A0,S_B0; keep s1(t+1) (S_A1,S_B1) in flight
        if (more) {
            asm volatile("s_waitcnt vmcnt(4)" ::: "memory");
            __builtin_amdgcn_s_barrier();
        }
    }

    // -------- epilogue (32x32 C/D: col = l&31, row = (r&3)+8*(r>>2)+4*kh) ----
    const long cb = (long)blockIdx.z * strC;
#pragma unroll
    for (int i = 0; i < 4; ++i) {
        const long rB = m0 + wr * 128 + i * 32 + 4 * kh;
#pragma unroll
        for (int j = 0; j < 2; ++j) {
            const long col = n0 + wc * 64 + j * 32 + r31;
#pragma unroll
            for (int r = 0; r < 16; ++r) {
                const long row = rB + (r & 3) + 8 * (r >> 2);
                float v = acc[i][j][r];
                if (EPI == 0) {
                    v += bias[row];
                    ((bf16*)Cp)[cb + row * (long)N + col] = __float2bfloat16(v);
                } else if (EPI == 1) {
                    v += bias[col];
                    v = gelu_exact(v);
                    ((bf16*)Cp)[cb + row * (long)N + col] = __float2bfloat16(v);
                } else {
                    v += bias[col] + Xadd[row * (long)N + col];
                    ((float*)Cp)[cb + row * (long)N + col] = v;
                }
            }
        }
    }
}

// ---------------- fp32 -> bf16 straight convert ----------------
__global__ void conv_bf16(const float* __restrict__ in, bf16* __restrict__ out, long n) {
    long i = ((long)blockIdx.x * 256 + threadIdx.x) * 4;
    if (i >= n) return;
    const float4 v = *(const float4*)(in + i);
    bf16 o[4] = {__float2bfloat16(v.x), __float2bfloat16(v.y),
                 __float2bfloat16(v.z), __float2bfloat16(v.w)};
    *(uint2*)(out + i) = *(uint2*)o;
}

// ---------------- fp32 (R x C) -> bf16 (C x R) transpose, z-batched ----------------
__global__ void transpose_f32_bf16(const float* __restrict__ in, bf16* __restrict__ out,
                                   int R, int C, long inStr, long outStr) {
    __shared__ float tl[64][65];
    const float* ip = in + (long)blockIdx.z * inStr;
    bf16* op = out + (long)blockIdx.z * outStr;
    const int r0 = blockIdx.y * 64, c0 = blockIdx.x * 64;
    const int tr = threadIdx.x >> 6, tc = threadIdx.x & 63;
#pragma unroll
    for (int k = 0; k < 16; k++) {
        int r = k * 4 + tr;
        tl[r][tc] = ip[(long)(r0 + r) * C + c0 + tc];
    }
    __syncthreads();
#pragma unroll
    for (int k = 0; k < 16; k++) {
        int r = k * 4 + tr;
        op[(long)(c0 + r) * R + r0 + tc] = __float2bfloat16(tl[tc][r]);
    }
}

// ---------------- serial part: phase cumsum + complex memory, one wave per (z,d) ----------------
__global__ __launch_bounds__(256) void scan_kernel(
    const bf16* __restrict__ omegaT, const bf16* __restrict__ xT,
    const float* __restrict__ log_scale, bf16* __restrict__ ctx,
    long strIn, long strCtx)
{
    const int d = blockIdx.x * 4 + (threadIdx.x >> 6);
    const int lane = threadIdx.x & 63;
    const float sc = expf(log_scale[d]);
    const bf16* po = omegaT + (long)blockIdx.z * strIn + (long)d * SS;
    const bf16* px = xT + (long)blockIdx.z * strIn + (long)d * SS;
    bf16* pc = ctx + (long)blockIdx.z * strCtx + (long)d * SS;

    float phi_c = 0.f, mr_c = 0.f, mi_c = 0.f;
    for (int tchunk = 0; tchunk < SS / 64; tchunk++) {
        const int s = tchunk * 64 + lane;
        const float pos = (float)(s + 1);
        float w = __bfloat162float(po[s]) * sc * rsqrtf(pos);
#pragma unroll
        for (int dlt = 1; dlt < 64; dlt <<= 1) {
            float v = __shfl_up(w, dlt, 64);
            if (lane >= dlt) w += v;
        }
        const float phi = phi_c + w;
        float sph, cph;
        sincosf(phi, &sph, &cph);
        const float xv = __bfloat162float(px[s]);
        const float cr = xv * cph, ci = xv * sph;
        float crs = cr, cis = ci;
#pragma unroll
        for (int dlt = 1; dlt < 64; dlt <<= 1) {
            float v1 = __shfl_up(crs, dlt, 64);
            float v2 = __shfl_up(cis, dlt, 64);
            if (lane >= dlt) { crs += v1; cis += v2; }
        }
        const float invp = 1.0f / pos;
        const float mr = (mr_c + crs) * invp;
        const float mi = (mi_c + cis) * invp;
        const float rr = mr * cph + mi * sph;
        const float ri = mi * cph - mr * sph;
        pc[s] = __float2bfloat16(cr);
        pc[(long)DD * SS + s] = __float2bfloat16(ci);
        pc[2L * DD * SS + s] = __float2bfloat16(rr);
        pc[3L * DD * SS + s] = __float2bfloat16(ri);
        phi_c += __shfl(w, 63, 64);
        mr_c += __shfl(crs, 63, 64);
        mi_c += __shfl(cis, 63, 64);
    }
}

// ---------------- per-s LN stats over f (split-f + atomics), z-batched ----------------
__global__ void zero_f32(float* p, int n) {
    int i = blockIdx.x * 256 + threadIdx.x;
    if (i < n) p[i] = 0.f;
}

__global__ void stats_kernel(const bf16* __restrict__ ctx, float* __restrict__ sums,
                             float* __restrict__ sqs) {
    const int s = blockIdx.x * 256 + threadIdx.x;  // 0..S-1
    const int f0 = blockIdx.y * 512;
    const int z = blockIdx.z;
    const bf16* p = ctx + (long)z * SD4 + (long)f0 * SS + s;
    float sm = 0.f, sq = 0.f;
#pragma unroll 8
    for (int f = 0; f < 512; f++) {
        float v = __bfloat162float(p[(long)f * SS]);
        sm += v;
        sq += v * v;
    }
    atomicAdd(&sums[z * SS + s], sm);
    atomicAdd(&sqs[z * SS + s], sq);
}

// ---------------- in-place LayerNorm + transpose (f,s)->(s,f), triangular pairs ----------------
__global__ __launch_bounds__(256) void lnt_pair(
    bf16* __restrict__ ctx, const float* __restrict__ sums, const float* __restrict__ sqs,
    const float* __restrict__ gamma, const float* __restrict__ beta)
{
    __shared__ float tA[64][65];
    __shared__ float tB[64][65];
    const int z = blockIdx.z;
    int rem = blockIdx.x, a = 0;
    for (int i = 0; i < 64; i++) {
        int cnt = 64 - i;
        if (rem < cnt) { a = i; break; }
        rem -= cnt;
    }
    const int b = a + rem;
    bf16* base = ctx + (long)z * SD4;
    const int tr = threadIdx.x >> 6, tc = threadIdx.x & 63;
    const float* sums_z = sums + z * SS;
    const float* sqs_z = sqs + z * SS;

#pragma unroll
    for (int k = 0; k < 16; k++) {
        int i = k * 4 + tr;
        tA[i][tc] = __bfloat162float(base[(long)(a * 64 + i) * SS + b * 64 + tc]);
    }
    if (a != b) {
#pragma unroll
        for (int k = 0; k < 16; k++) {
            int i = k * 4 + tr;
            tB[i][tc] = __bfloat162float(base[(long)(b * 64 + i) * SS + a * 64 + tc]);
        }
    }
    __syncthreads();

    {
        const float g = gamma[a * 64 + tc], be = beta[a * 64 + tc];
#pragma unroll
        for (int k = 0; k < 16; k++) {
            const int i = k * 4 + tr;
            const int s = b * 64 + i;
            const float mu = sums_z[s] * (1.0f / FD);
            const float var = sqs_z[s] * (1.0f / FD) - mu * mu;
            const float is = rsqrtf(var + 1e-5f);
            const float v = (tA[tc][i] - mu) * is * g + be;
            base[(long)s * FD + a * 64 + tc] = __float2bfloat16(v);
        }
    }
    if (a != b) {
        const float g = gamma[b * 64 + tc], be = beta[b * 64 + tc];
#pragma unroll
        for (int k = 0; k < 16; k++) {
            const int i = k * 4 + tr;
            const int s = a * 64 + i;
            const float mu = sums_z[s] * (1.0f / FD);
            const float var = sqs_z[s] * (1.0f / FD) - mu * mu;
            const float is = rsqrtf(var + 1e-5f);
            const float v = (tB[tc][i] - mu) * is * g + be;
            base[(long)s * FD + b * 64 + tc] = __float2bfloat16(v);
        }
    }
}

// ---------------- launch ----------------
extern "C" void kernel_launch(void* const* d_in, const int* in_sizes, int n_in,
                              void* d_out, int out_size, void* d_ws, size_t ws_size,
                              hipStream_t stream)
{
    const float* x = (const float*)d_in[0];
    const float* Wo = (const float*)d_in[1];
    const float* bo = (const float*)d_in[2];
    const float* lsc = (const float*)d_in[3];
    const float* gam = (const float*)d_in[4];
    const float* bet = (const float*)d_in[5];
    const float* W1 = (const float*)d_in[6];
    const float* b1 = (const float*)d_in[7];
    const float* W2 = (const float*)d_in[8];
    const float* b2 = (const float*)d_in[9];

    static bool attr_done = false;
    if (!attr_done) {
        hipFuncSetAttribute(reinterpret_cast<const void*>(gemm256<0>),
                            hipFuncAttributeMaxDynamicSharedMemorySize, 131072);
        hipFuncSetAttribute(reinterpret_cast<const void*>(gemm256<1>),
                            hipFuncAttributeMaxDynamicSharedMemorySize, 131072);
        hipFuncSetAttribute(reinterpret_cast<const void*>(gemm256<2>),
                            hipFuncAttributeMaxDynamicSharedMemorySize, 131072);
        attr_done = true;
    }

    char* ws = (char*)d_ws;
    const size_t MB = 1024 * 1024;

    bf16* W1T = (bf16*)(ws + 0);           // 16 MB  (2048 x 4096)
    bf16* W2T = (bf16*)(ws + 16 * MB);     //  4 MB  (1024 x 2048)
    bf16* WoT = (bf16*)(ws + 20 * MB);     //  2 MB  (1024 x 1024)
    float* sums = (float*)(ws + 22 * MB);  // 4*SS floats
    float* sqs = sums + 4 * SS;

    transpose_f32_bf16<<<dim3(DD / 64, DD / 64, 1), 256, 0, stream>>>(Wo, WoT, DD, DD, 0, 0);
    transpose_f32_bf16<<<dim3(GDIM / 64, FD / 64, 1), 256, 0, stream>>>(W1, W1T, FD, GDIM, 0, 0);
    transpose_f32_bf16<<<dim3(DD / 64, GDIM / 64, 1), 256, 0, stream>>>(W2, W2T, GDIM, DD, 0, 0);

    const int NPAIR = 64 * 65 / 2;

    if (ws_size >= 220 * MB) {
        bf16* xT  = (bf16*)(ws + 23 * MB);
        bf16* omT = (bf16*)(ws + 55 * MB);
        bf16* ctx = (bf16*)(ws + 87 * MB);
        bf16* xb  = (bf16*)(ws + 87 * MB);
        bf16* h1  = (bf16*)(ws + 23 * MB);

        conv_bf16<<<(int)(BB * SD / 1024), 256, 0, stream>>>(x, xb, BB * SD);
        transpose_f32_bf16<<<dim3(DD / 64, SS / 64, BB), 256, 0, stream>>>(x, xT, SS, DD, SD, SD);

        // GEMM1 batched: omega^T[b] = Wo^T * x[b]^T   (M=1024, N=4096, K=1024)
        gemm256<0><<<dim3(SS / 256, DD / 256, BB), 512, 131072, stream>>>(
            WoT, xb, omT, bo, nullptr, DD, SS, DD, 0L, SD, SD);

        scan_kernel<<<dim3(DD / 4, 1, BB), 256, 0, stream>>>(omT, xT, lsc, ctx, SD, SD4);

        zero_f32<<<(8 * SS + 255) / 256, 256, 0, stream>>>(sums, 8 * SS);
        stats_kernel<<<dim3(SS / 256, FD / 512, BB), 256, 0, stream>>>(ctx, sums, sqs);

        lnt_pair<<<dim3(NPAIR, 1, BB), 256, 0, stream>>>(ctx, sums, sqs, gam, bet);

        // GEMM2 (M=16384, N=2048, K=4096): h1 = gelu(hln * W1 + b1)
        gemm256<1><<<dim3(GDIM / 256, BB * SS / 256, 1), 512, 131072, stream>>>(
            ctx, W1T, h1, b1, nullptr, BB * SS, GDIM, FD, 0L, 0L, 0L);

        // GEMM3 (M=16384, N=1024, K=2048): out = x + h1 * W2 + b2, fp32
        gemm256<2><<<dim3(DD / 256, BB * SS / 256, 1), 512, 131072, stream>>>(
            h1, W2T, d_out, b2, x, BB * SS, DD, GDIM, 0L, 0L, 0L);
    } else {
        bf16* xb  = (bf16*)(ws + 23 * MB);
        bf16* ctx = (bf16*)(ws + 23 * MB);
        bf16* omT = (bf16*)(ws + 55 * MB);
        bf16* xT  = (bf16*)(ws + 63 * MB);
        bf16* h1  = (bf16*)(ws + 55 * MB);

        for (int b = 0; b < BB; b++) {
            const float* xbf = x + (long)b * SD;
            conv_bf16<<<(int)(SD / 1024), 256, 0, stream>>>(xbf, xb, SD);
            transpose_f32_bf16<<<dim3(DD / 64, SS / 64, 1), 256, 0, stream>>>(xbf, xT, SS, DD, 0, 0);
            gemm256<0><<<dim3(SS / 256, DD / 256, 1), 512, 131072, stream>>>(
                WoT, xb, omT, bo, nullptr, DD, SS, DD, 0L, 0L, 0L);
            scan_kernel<<<dim3(DD / 4, 1, 1), 256, 0, stream>>>(omT, xT, lsc, ctx, 0L, 0L);
            zero_f32<<<(2 * SS + 255) / 256, 256, 0, stream>>>(sums, 2 * SS);
            stats_kernel<<<dim3(SS / 256, FD / 512, 1), 256, 0, stream>>>(ctx, sums, sqs);
            lnt_pair<<<dim3(NPAIR, 1, 1), 256, 0, stream>>>(ctx, sums, sqs, gam, bet);
            gemm256<1><<<dim3(GDIM / 256, SS / 256, 1), 512, 131072, stream>>>(
                ctx, W1T, h1, b1, nullptr, SS, GDIM, FD, 0L, 0L, 0L);
            gemm256<2><<<dim3(DD / 256, SS / 256, 1), 512, 131072, stream>>>(
                h1, W2T, (float*)d_out + (long)b * SD, b2, xbf, SS, DD, GDIM, 0L, 0L, 0L);
        }
    }
}

// Round 6
// 777.478 us; speedup vs baseline: 1.0220x; 1.0220x over previous
//
#include <hip/hip_runtime.h>
#include <hip/hip_bf16.h>
#include <math.h>

typedef __hip_bfloat16 bf16;
typedef __attribute__((ext_vector_type(8))) short bf16x8;
typedef __attribute__((ext_vector_type(4))) float f32x4;
typedef __attribute__((ext_vector_type(16))) float f32x16;

static constexpr int DD = 1024;    // D
static constexpr int BB = 4;       // batch
static constexpr int SS = 4096;    // seq
static constexpr int FD = 4096;    // 4D
static constexpr int GDIM = 2048;  // 2D
static constexpr long SD = (long)SS * DD;   // per-batch x elements (4M)
static constexpr long SD4 = 4 * SD;         // per-batch ctx elements

// ---------------- async global->LDS (16B per lane) ----------------
__device__ __forceinline__ void gl2lds16(const bf16* g, bf16* l) {
    __builtin_amdgcn_global_load_lds(
        (const __attribute__((address_space(1))) void*)g,
        (__attribute__((address_space(3))) void*)l, 16, 0, 0);
}

// ---------------- branchless exact-erf GELU (A&S 7.1.26, |eps|<=1.5e-7) -----
__device__ __forceinline__ float gelu_exact(float v) {
    const float ax = fabsf(v) * 0.70710678118654752f;  // |v|/sqrt(2)
    const float t = 1.0f / (1.0f + 0.3275911f * ax);
    const float poly = t * (0.254829592f + t * (-0.284496736f +
                       t * (1.421413741f + t * (-1.453152027f + t * 1.061405429f))));
    const float er = 1.0f - poly * __expf(-ax * ax);
    const float erfv = v < 0.f ? -er : er;
    return 0.5f * v * (1.0f + erfv);
}

// ================= 256x256 GEMM, 32x32x16 MFMA, 2 barriers/K-tile ==========
// C[M,N] = A[M,K] * BT[N,K]^T, bf16 in, z-batched via strides.
// BM=BN=256, BK=64, 512 threads = 8 waves (2Mx4N), per-wave output 128x64.
// LDS 128 KiB: A/B each [2 buf][2 kslice][256 rows][32 k] bf16.
// Fragment reads use 4 PER-LANE BASE offsets (A/B x k-half) + wave-uniform
// constant offsets (i*1024 / j*1024 elems) -> compiler emits clean
// ds_read_b128 base+offset:N (round-2 idiom; fixes round-5's 2.5e7 bank
// conflicts from per-read XOR address recomputation).
// Counted vmcnt: vmcnt(6) mid-tile, vmcnt(4) end-of-tile; never 0 in
// steady state. LDS swizzle: 16B chunk c at row r holds global chunk
// c ^ ((r>>1)&3); applied on per-lane GLOBAL source (linear gl2lds dest)
// and on the per-lane read base.
// 32x32x16 lane maps: A/B: row/col = l&31, k = (l>>5)*8+e within 16-slice;
// C/D: col = l&31, row = (r&3)+8*(r>>2)+4*(l>>5), r=0..15.
// EPI 0: +bias[row], bf16   EPI 1: +bias[col], gelu, bf16   EPI 2: +bias[col]+X, f32
template <int EPI>
__global__ __launch_bounds__(512, 2) void gemm256(
    const bf16* __restrict__ A, const bf16* __restrict__ BT, void* __restrict__ Cp,
    const float* __restrict__ bias, const float* __restrict__ Xadd,
    int M, int N, int K, long strA, long strBT, long strC)
{
    extern __shared__ bf16 lds[];  // 65536 elems: A [0,32768), B [32768,65536)
    const int tid = threadIdx.x;
    const int l = tid & 63, wv = tid >> 6;
    const int wr = wv >> 2, wc = wv & 3;

    // T1: bijective XCD swizzle over the per-z 2D grid
    int lin = blockIdx.y * gridDim.x + blockIdx.x;
    {
        const int nwg = gridDim.x * gridDim.y;
        const int qq = nwg >> 3, rr = nwg & 7;
        const int xcd = lin & 7, idx = lin >> 3;
        lin = (xcd < rr ? xcd * (qq + 1) : rr * (qq + 1) + (xcd - rr) * qq) + idx;
    }
    const long m0 = (long)(lin / gridDim.x) * 256;
    const long n0 = (long)(lin % gridDim.x) * 256;

    A += (long)blockIdx.z * strA;
    BT += (long)blockIdx.z * strBT;

    // staging: thread t covers row (t>>2) [+128 for 2nd inst], 16B chunk (t&3),
    // source pre-swizzled: global chunk = (t&3) ^ ((row>>1)&3)
    const int schunk = (tid & 3) ^ ((tid >> 3) & 3);
    const bf16* pa = A + (m0 + (tid >> 2)) * (long)K + schunk * 8;
    const bf16* pb = BT + (n0 + (tid >> 2)) * (long)K + schunk * 8;
    const long rowK = 128L * (long)K;
    const int stgOff = wv * 512;  // wave-uniform 1 KiB slot

    // 32x32 fragment lane decomposition + hoisted per-lane read offsets
    const int r31 = l & 31, kh = l >> 5;
    const int swz = (r31 >> 1) & 3;
    const int ch0 = (kh ^ swz) * 8;          // k-half 0 chunk offset (elems)
    const int ch1 = ((kh + 2) ^ swz) * 8;    // k-half 1 chunk offset (elems)
    const int offB0 = (wc * 64 + r31) * 32 + ch0;
    const int offB1 = (wc * 64 + r31) * 32 + ch1;
    const int offA0 = (wr * 128 + r31) * 32 + ch0;
    const int offA1 = (wr * 128 + r31) * 32 + ch1;

    f32x16 acc[4][2];
#pragma unroll
    for (int i = 0; i < 4; ++i)
#pragma unroll
        for (int j = 0; j < 2; ++j)
#pragma unroll
            for (int r = 0; r < 16; ++r) acc[i][j][r] = 0.f;

    const int NT = K >> 6;

    // ---- prologue: stage all 4 halves of tile 0 into buf0
    {
        bf16* dA0 = lds + stgOff;
        bf16* dA1 = lds + 8192 + stgOff;
        bf16* dB0 = lds + 32768 + stgOff;
        bf16* dB1 = lds + 40960 + stgOff;
        gl2lds16(pa, dA0);       gl2lds16(pa + rowK, dA0 + 4096);
        gl2lds16(pb, dB0);       gl2lds16(pb + rowK, dB0 + 4096);
        gl2lds16(pa + 32, dA1);  gl2lds16(pa + 32 + rowK, dA1 + 4096);
        gl2lds16(pb + 32, dB1);  gl2lds16(pb + 32 + rowK, dB1 + 4096);
        asm volatile("s_waitcnt vmcnt(4)" ::: "memory");  // s0 done, s1 (4) in flight
        __builtin_amdgcn_s_barrier();
    }

    for (int t = 0; t < NT; ++t) {
        const int buf = t & 1;
        const bool more = (t + 1) < NT;
        const long ko = (long)(t + 1) * 64;
        const bf16* As0 = lds + buf * 16384;
        const bf16* As1 = As0 + 8192;
        const bf16* Bs0 = lds + 32768 + buf * 16384;
        const bf16* Bs1 = Bs0 + 8192;
        bf16* nA0 = lds + (buf ^ 1) * 16384 + stgOff;
        bf16* nA1 = nA0 + 8192;
        bf16* nB0 = lds + 32768 + (buf ^ 1) * 16384 + stgOff;
        bf16* nB1 = nB0 + 8192;

        // ================= half 0 (kslice 0) =================
        {
            bf16x8 bq[2][2], af[4][2];
            const bf16* b0 = Bs0 + offB0;
            const bf16* b1 = Bs0 + offB1;
            const bf16* a0 = As0 + offA0;
            const bf16* a1 = As0 + offA1;
#pragma unroll
            for (int j = 0; j < 2; ++j) {
                bq[j][0] = *(const bf16x8*)(b0 + j * 1024);
                bq[j][1] = *(const bf16x8*)(b1 + j * 1024);
            }
#pragma unroll
            for (int i = 0; i < 4; ++i) {
                af[i][0] = *(const bf16x8*)(a0 + i * 1024);
                af[i][1] = *(const bf16x8*)(a1 + i * 1024);
            }
            if (more) {
                gl2lds16(pa + ko, nA0); gl2lds16(pa + ko + rowK, nA0 + 4096);   // S_A0
                gl2lds16(pb + ko, nB0); gl2lds16(pb + ko + rowK, nB0 + 4096);   // S_B0
            }
            __builtin_amdgcn_s_setprio(1);
#pragma unroll
            for (int i = 0; i < 4; ++i)
#pragma unroll
                for (int j = 0; j < 2; ++j)
                    acc[i][j] = __builtin_amdgcn_mfma_f32_32x32x16_bf16(af[i][0], bq[j][0], acc[i][j], 0, 0, 0);
            __builtin_amdgcn_s_setprio(0);
            if (more) { gl2lds16(pa + ko + 32, nA1); gl2lds16(pa + ko + 32 + rowK, nA1 + 4096); }  // S_A1
            __builtin_amdgcn_s_setprio(1);
#pragma unroll
            for (int i = 0; i < 4; ++i)
#pragma unroll
                for (int j = 0; j < 2; ++j)
                    acc[i][j] = __builtin_amdgcn_mfma_f32_32x32x16_bf16(af[i][1], bq[j][1], acc[i][j], 0, 0, 0);
            __builtin_amdgcn_s_setprio(0);
        }
        // publish s1(t): retire the 4 oldest (s1 stages from tile t-1 / prologue)
        if (more) asm volatile("s_waitcnt vmcnt(6)" ::: "memory");
        else      asm volatile("s_waitcnt vmcnt(0)" ::: "memory");
        __builtin_amdgcn_s_barrier();

        // ================= half 1 (kslice 1) =================
        {
            bf16x8 bq[2][2], af[4][2];
            const bf16* b0 = Bs1 + offB0;
            const bf16* b1 = Bs1 + offB1;
            const bf16* a0 = As1 + offA0;
            const bf16* a1 = As1 + offA1;
#pragma unroll
            for (int j = 0; j < 2; ++j) {
                bq[j][0] = *(const bf16x8*)(b0 + j * 1024);
                bq[j][1] = *(const bf16x8*)(b1 + j * 1024);
            }
#pragma unroll
            for (int i = 0; i < 4; ++i) {
                af[i][0] = *(const bf16x8*)(a0 + i * 1024);
                af[i][1] = *(const bf16x8*)(a1 + i * 1024);
            }
            if (more) { gl2lds16(pb + ko + 32, nB1); gl2lds16(pb + ko + 32 + rowK, nB1 + 4096); }  // S_B1
            __builtin_amdgcn_s_setprio(1);
#pragma unroll
            for (int i = 0; i < 4; ++i)
#pragma unroll
                for (int j = 0; j < 2; ++j)
                    acc[i][j] = __builtin_amdgcn_mfma_f32_32x32x16_bf16(af[i][0], bq[j][0], acc[i][j], 0, 0, 0);
            __builtin_amdgcn_s_setprio(0);
            __builtin_amdgcn_s_setprio(1);
#pragma unroll
            for (int i = 0; i < 4; ++i)
#pragma unroll
                for (int j = 0; j < 2; ++j)
                    acc[i][j] = __builtin_amdgcn_mfma_f32_32x32x16_bf16(af[i][1], bq[j][1], acc[i][j], 0, 0, 0);
            __builtin_amdgcn_s_setprio(0);
        }
        // publish s0(t+1): retire S_A0,S_B0; keep s1(t+1) (S_A1,S_B1) in flight
        if (more) {
            asm volatile("s_waitcnt vmcnt(4)" ::: "memory");
            __builtin_amdgcn_s_barrier();
        }
    }

    // -------- epilogue (32x32 C/D: col = l&31, row = (r&3)+8*(r>>2)+4*kh) ----
    const long cb = (long)blockIdx.z * strC;
#pragma unroll
    for (int i = 0; i < 4; ++i) {
        const long rB = m0 + wr * 128 + i * 32 + 4 * kh;
#pragma unroll
        for (int j = 0; j < 2; ++j) {
            const long col = n0 + wc * 64 + j * 32 + r31;
#pragma unroll
            for (int r = 0; r < 16; ++r) {
                const long row = rB + (r & 3) + 8 * (r >> 2);
                float v = acc[i][j][r];
                if (EPI == 0) {
                    v += bias[row];
                    ((bf16*)Cp)[cb + row * (long)N + col] = __float2bfloat16(v);
                } else if (EPI == 1) {
                    v += bias[col];
                    v = gelu_exact(v);
                    ((bf16*)Cp)[cb + row * (long)N + col] = __float2bfloat16(v);
                } else {
                    v += bias[col] + Xadd[row * (long)N + col];
                    ((float*)Cp)[cb + row * (long)N + col] = v;
                }
            }
        }
    }
}

// ---------------- fp32 -> bf16 straight convert ----------------
__global__ void conv_bf16(const float* __restrict__ in, bf16* __restrict__ out, long n) {
    long i = ((long)blockIdx.x * 256 + threadIdx.x) * 4;
    if (i >= n) return;
    const float4 v = *(const float4*)(in + i);
    bf16 o[4] = {__float2bfloat16(v.x), __float2bfloat16(v.y),
                 __float2bfloat16(v.z), __float2bfloat16(v.w)};
    *(uint2*)(out + i) = *(uint2*)o;
}

// ---------------- fp32 (R x C) -> bf16 (C x R) transpose, z-batched ----------------
__global__ void transpose_f32_bf16(const float* __restrict__ in, bf16* __restrict__ out,
                                   int R, int C, long inStr, long outStr) {
    __shared__ float tl[64][65];
    const float* ip = in + (long)blockIdx.z * inStr;
    bf16* op = out + (long)blockIdx.z * outStr;
    const int r0 = blockIdx.y * 64, c0 = blockIdx.x * 64;
    const int tr = threadIdx.x >> 6, tc = threadIdx.x & 63;
#pragma unroll
    for (int k = 0; k < 16; k++) {
        int r = k * 4 + tr;
        tl[r][tc] = ip[(long)(r0 + r) * C + c0 + tc];
    }
    __syncthreads();
#pragma unroll
    for (int k = 0; k < 16; k++) {
        int r = k * 4 + tr;
        op[(long)(c0 + r) * R + r0 + tc] = __float2bfloat16(tl[tc][r]);
    }
}

// ---------------- serial part: phase cumsum + complex memory, one wave per (z,d) ----------------
__global__ __launch_bounds__(256) void scan_kernel(
    const bf16* __restrict__ omegaT, const bf16* __restrict__ xT,
    const float* __restrict__ log_scale, bf16* __restrict__ ctx,
    long strIn, long strCtx)
{
    const int d = blockIdx.x * 4 + (threadIdx.x >> 6);
    const int lane = threadIdx.x & 63;
    const float sc = expf(log_scale[d]);
    const bf16* po = omegaT + (long)blockIdx.z * strIn + (long)d * SS;
    const bf16* px = xT + (long)blockIdx.z * strIn + (long)d * SS;
    bf16* pc = ctx + (long)blockIdx.z * strCtx + (long)d * SS;

    float phi_c = 0.f, mr_c = 0.f, mi_c = 0.f;
    for (int tchunk = 0; tchunk < SS / 64; tchunk++) {
        const int s = tchunk * 64 + lane;
        const float pos = (float)(s + 1);
        float w = __bfloat162float(po[s]) * sc * rsqrtf(pos);
#pragma unroll
        for (int dlt = 1; dlt < 64; dlt <<= 1) {
            float v = __shfl_up(w, dlt, 64);
            if (lane >= dlt) w += v;
        }
        const float phi = phi_c + w;
        float sph, cph;
        sincosf(phi, &sph, &cph);
        const float xv = __bfloat162float(px[s]);
        const float cr = xv * cph, ci = xv * sph;
        float crs = cr, cis = ci;
#pragma unroll
        for (int dlt = 1; dlt < 64; dlt <<= 1) {
            float v1 = __shfl_up(crs, dlt, 64);
            float v2 = __shfl_up(cis, dlt, 64);
            if (lane >= dlt) { crs += v1; cis += v2; }
        }
        const float invp = 1.0f / pos;
        const float mr = (mr_c + crs) * invp;
        const float mi = (mi_c + cis) * invp;
        const float rr = mr * cph + mi * sph;
        const float ri = mi * cph - mr * sph;
        pc[s] = __float2bfloat16(cr);
        pc[(long)DD * SS + s] = __float2bfloat16(ci);
        pc[2L * DD * SS + s] = __float2bfloat16(rr);
        pc[3L * DD * SS + s] = __float2bfloat16(ri);
        phi_c += __shfl(w, 63, 64);
        mr_c += __shfl(crs, 63, 64);
        mi_c += __shfl(cis, 63, 64);
    }
}

// ---------------- per-s LN stats over f (split-f + atomics), z-batched ----------------
__global__ void zero_f32(float* p, int n) {
    int i = blockIdx.x * 256 + threadIdx.x;
    if (i < n) p[i] = 0.f;
}

__global__ void stats_kernel(const bf16* __restrict__ ctx, float* __restrict__ sums,
                             float* __restrict__ sqs) {
    const int s = blockIdx.x * 256 + threadIdx.x;  // 0..S-1
    const int f0 = blockIdx.y * 512;
    const int z = blockIdx.z;
    const bf16* p = ctx + (long)z * SD4 + (long)f0 * SS + s;
    float sm = 0.f, sq = 0.f;
#pragma unroll 8
    for (int f = 0; f < 512; f++) {
        float v = __bfloat162float(p[(long)f * SS]);
        sm += v;
        sq += v * v;
    }
    atomicAdd(&sums[z * SS + s], sm);
    atomicAdd(&sqs[z * SS + s], sq);
}

// ---------------- in-place LayerNorm + transpose (f,s)->(s,f), triangular pairs ----------------
__global__ __launch_bounds__(256) void lnt_pair(
    bf16* __restrict__ ctx, const float* __restrict__ sums, const float* __restrict__ sqs,
    const float* __restrict__ gamma, const float* __restrict__ beta)
{
    __shared__ float tA[64][65];
    __shared__ float tB[64][65];
    const int z = blockIdx.z;
    int rem = blockIdx.x, a = 0;
    for (int i = 0; i < 64; i++) {
        int cnt = 64 - i;
        if (rem < cnt) { a = i; break; }
        rem -= cnt;
    }
    const int b = a + rem;
    bf16* base = ctx + (long)z * SD4;
    const int tr = threadIdx.x >> 6, tc = threadIdx.x & 63;
    const float* sums_z = sums + z * SS;
    const float* sqs_z = sqs + z * SS;

#pragma unroll
    for (int k = 0; k < 16; k++) {
        int i = k * 4 + tr;
        tA[i][tc] = __bfloat162float(base[(long)(a * 64 + i) * SS + b * 64 + tc]);
    }
    if (a != b) {
#pragma unroll
        for (int k = 0; k < 16; k++) {
            int i = k * 4 + tr;
            tB[i][tc] = __bfloat162float(base[(long)(b * 64 + i) * SS + a * 64 + tc]);
        }
    }
    __syncthreads();

    {
        const float g = gamma[a * 64 + tc], be = beta[a * 64 + tc];
#pragma unroll
        for (int k = 0; k < 16; k++) {
            const int i = k * 4 + tr;
            const int s = b * 64 + i;
            const float mu = sums_z[s] * (1.0f / FD);
            const float var = sqs_z[s] * (1.0f / FD) - mu * mu;
            const float is = rsqrtf(var + 1e-5f);
            const float v = (tA[tc][i] - mu) * is * g + be;
            base[(long)s * FD + a * 64 + tc] = __float2bfloat16(v);
        }
    }
    if (a != b) {
        const float g = gamma[b * 64 + tc], be = beta[b * 64 + tc];
#pragma unroll
        for (int k = 0; k < 16; k++) {
            const int i = k * 4 + tr;
            const int s = a * 64 + i;
            const float mu = sums_z[s] * (1.0f / FD);
            const float var = sqs_z[s] * (1.0f / FD) - mu * mu;
            const float is = rsqrtf(var + 1e-5f);
            const float v = (tB[tc][i] - mu) * is * g + be;
            base[(long)s * FD + b * 64 + tc] = __float2bfloat16(v);
        }
    }
}

// ---------------- launch ----------------
extern "C" void kernel_launch(void* const* d_in, const int* in_sizes, int n_in,
                              void* d_out, int out_size, void* d_ws, size_t ws_size,
                              hipStream_t stream)
{
    const float* x = (const float*)d_in[0];
    const float* Wo = (const float*)d_in[1];
    const float* bo = (const float*)d_in[2];
    const float* lsc = (const float*)d_in[3];
    const float* gam = (const float*)d_in[4];
    const float* bet = (const float*)d_in[5];
    const float* W1 = (const float*)d_in[6];
    const float* b1 = (const float*)d_in[7];
    const float* W2 = (const float*)d_in[8];
    const float* b2 = (const float*)d_in[9];

    static bool attr_done = false;
    if (!attr_done) {
        hipFuncSetAttribute(reinterpret_cast<const void*>(gemm256<0>),
                            hipFuncAttributeMaxDynamicSharedMemorySize, 131072);
        hipFuncSetAttribute(reinterpret_cast<const void*>(gemm256<1>),
                            hipFuncAttributeMaxDynamicSharedMemorySize, 131072);
        hipFuncSetAttribute(reinterpret_cast<const void*>(gemm256<2>),
                            hipFuncAttributeMaxDynamicSharedMemorySize, 131072);
        attr_done = true;
    }

    char* ws = (char*)d_ws;
    const size_t MB = 1024 * 1024;

    bf16* W1T = (bf16*)(ws + 0);           // 16 MB  (2048 x 4096)
    bf16* W2T = (bf16*)(ws + 16 * MB);     //  4 MB  (1024 x 2048)
    bf16* WoT = (bf16*)(ws + 20 * MB);     //  2 MB  (1024 x 1024)
    float* sums = (float*)(ws + 22 * MB);  // 4*SS floats
    float* sqs = sums + 4 * SS;

    transpose_f32_bf16<<<dim3(DD / 64, DD / 64, 1), 256, 0, stream>>>(Wo, WoT, DD, DD, 0, 0);
    transpose_f32_bf16<<<dim3(GDIM / 64, FD / 64, 1), 256, 0, stream>>>(W1, W1T, FD, GDIM, 0, 0);
    transpose_f32_bf16<<<dim3(DD / 64, GDIM / 64, 1), 256, 0, stream>>>(W2, W2T, GDIM, DD, 0, 0);

    const int NPAIR = 64 * 65 / 2;

    if (ws_size >= 220 * MB) {
        bf16* xT  = (bf16*)(ws + 23 * MB);
        bf16* omT = (bf16*)(ws + 55 * MB);
        bf16* ctx = (bf16*)(ws + 87 * MB);
        bf16* xb  = (bf16*)(ws + 87 * MB);
        bf16* h1  = (bf16*)(ws + 23 * MB);

        conv_bf16<<<(int)(BB * SD / 1024), 256, 0, stream>>>(x, xb, BB * SD);
        transpose_f32_bf16<<<dim3(DD / 64, SS / 64, BB), 256, 0, stream>>>(x, xT, SS, DD, SD, SD);

        // GEMM1 batched: omega^T[b] = Wo^T * x[b]^T   (M=1024, N=4096, K=1024)
        gemm256<0><<<dim3(SS / 256, DD / 256, BB), 512, 131072, stream>>>(
            WoT, xb, omT, bo, nullptr, DD, SS, DD, 0L, SD, SD);

        scan_kernel<<<dim3(DD / 4, 1, BB), 256, 0, stream>>>(omT, xT, lsc, ctx, SD, SD4);

        zero_f32<<<(8 * SS + 255) / 256, 256, 0, stream>>>(sums, 8 * SS);
        stats_kernel<<<dim3(SS / 256, FD / 512, BB), 256, 0, stream>>>(ctx, sums, sqs);

        lnt_pair<<<dim3(NPAIR, 1, BB), 256, 0, stream>>>(ctx, sums, sqs, gam, bet);

        // GEMM2 (M=16384, N=2048, K=4096): h1 = gelu(hln * W1 + b1)
        gemm256<1><<<dim3(GDIM / 256, BB * SS / 256, 1), 512, 131072, stream>>>(
            ctx, W1T, h1, b1, nullptr, BB * SS, GDIM, FD, 0L, 0L, 0L);

        // GEMM3 (M=16384, N=1024, K=2048): out = x + h1 * W2 + b2, fp32
        gemm256<2><<<dim3(DD / 256, BB * SS / 256, 1), 512, 131072, stream>>>(
            h1, W2T, d_out, b2, x, BB * SS, DD, GDIM, 0L, 0L, 0L);
    } else {
        bf16* xb  = (bf16*)(ws + 23 * MB);
        bf16* ctx = (bf16*)(ws + 23 * MB);
        bf16* omT = (bf16*)(ws + 55 * MB);
        bf16* xT  = (bf16*)(ws + 63 * MB);
        bf16* h1  = (bf16*)(ws + 55 * MB);

        for (int b = 0; b < BB; b++) {
            const float* xbf = x + (long)b * SD;
            conv_bf16<<<(int)(SD / 1024), 256, 0, stream>>>(xbf, xb, SD);
            transpose_f32_bf16<<<dim3(DD / 64, SS / 64, 1), 256, 0, stream>>>(xbf, xT, SS, DD, 0, 0);
            gemm256<0><<<dim3(SS / 256, DD / 256, 1), 512, 131072, stream>>>(
                WoT, xb, omT, bo, nullptr, DD, SS, DD, 0L, 0L, 0L);
            scan_kernel<<<dim3(DD / 4, 1, 1), 256, 0, stream>>>(omT, xT, lsc, ctx, 0L, 0L);
            zero_f32<<<(2 * SS + 255) / 256, 256, 0, stream>>>(sums, 2 * SS);
            stats_kernel<<<dim3(SS / 256, FD / 512, 1), 256, 0, stream>>>(ctx, sums, sqs);
            lnt_pair<<<dim3(NPAIR, 1, 1), 256, 0, stream>>>(ctx, sums, sqs, gam, bet);
            gemm256<1><<<dim3(GDIM / 256, SS / 256, 1), 512, 131072, stream>>>(
                ctx, W1T, h1, b1, nullptr, SS, GDIM, FD, 0L, 0L, 0L);
            gemm256<2><<<dim3(DD / 256, SS / 256, 1), 512, 131072, stream>>>(
                h1, W2T, (float*)d_out + (long)b * SD, b2, xbf, SS, DD, GDIM, 0L, 0L, 0L);
        }
    }
}

// Round 7
// 764.224 us; speedup vs baseline: 1.0397x; 1.0173x over previous
//
#include <hip/hip_runtime.h>
#include <hip/hip_bf16.h>
#include <math.h>

typedef __hip_bfloat16 bf16;
typedef __attribute__((ext_vector_type(8))) short bf16x8;
typedef __attribute__((ext_vector_type(4))) float f32x4;

static constexpr int DD = 1024;    // D
static constexpr int BB = 4;       // batch
static constexpr int SS = 4096;    // seq
static constexpr int FD = 4096;    // 4D
static constexpr int GDIM = 2048;  // 2D
static constexpr long SD = (long)SS * DD;   // per-batch x elements (4M)
static constexpr long SD4 = 4 * SD;         // per-batch ctx elements

// ---------------- async global->LDS (16B per lane) ----------------
__device__ __forceinline__ void gl2lds16(const bf16* g, bf16* l) {
    __builtin_amdgcn_global_load_lds(
        (const __attribute__((address_space(1))) void*)g,
        (__attribute__((address_space(3))) void*)l, 16, 0, 0);
}

// ---------------- branchless exact-erf GELU (A&S 7.1.26, |eps|<=1.5e-7) -----
__device__ __forceinline__ float gelu_exact(float v) {
    const float ax = fabsf(v) * 0.70710678118654752f;  // |v|/sqrt(2)
    const float t = 1.0f / (1.0f + 0.3275911f * ax);
    const float poly = t * (0.254829592f + t * (-0.284496736f +
                       t * (1.421413741f + t * (-1.453152027f + t * 1.061405429f))));
    const float er = 1.0f - poly * __expf(-ax * ax);
    const float erfv = v < 0.f ? -er : er;
    return 0.5f * v * (1.0f + erfv);
}

__device__ __forceinline__ float bf2f(unsigned short us) {
    return __uint_as_float(((unsigned)us) << 16);
}

// ================= 256x256 GEMM, 16x16x32 MFMA, 2 barriers/K-tile ==========
// (verified round-2 core: 0 bank conflicts, GEMM2 284us, MfmaUtil 44)
// C[M,N] = A[M,K] * BT[N,K]^T, bf16 in, z-batched via strides.
// BM=BN=256, BK=64, 512 threads = 8 waves (2Mx4N), per-wave output 128x64.
// LDS 128 KiB: A/B each [2 buf][2 kslice][256 rows][32 k] bf16.
// Counted vmcnt: vmcnt(6) mid-tile, vmcnt(4) end-of-tile; never 0 steady.
// LDS swizzle: 16B chunk c at row r holds global chunk c ^ ((r>>1)&3).
// EPI 0: +bias[row], bf16
// EPI 1: LN-FOLDED epilogue: v = is[s]*acc - (is*mu)[s]*u[col]
//        + t[col] + bias[col]; gelu; bf16.   (A = RAW ctx, B = gamma-scaled W1T)
// EPI 2: +bias[col]+X[row,col], f32
template <int EPI>
__global__ __launch_bounds__(512, 2) void gemm256(
    const bf16* __restrict__ A, const bf16* __restrict__ BT, void* __restrict__ Cp,
    const float* __restrict__ bias, const float* __restrict__ Xadd,
    const float2* __restrict__ is2, const float* __restrict__ uArr,
    const float* __restrict__ tArr,
    int M, int N, int K, long strA, long strBT, long strC)
{
    extern __shared__ bf16 lds[];  // 65536 elems: A [0,32768), B [32768,65536)
    const int tid = threadIdx.x;
    const int l = tid & 63, wv = tid >> 6;
    const int wr = wv >> 2, wc = wv & 3;

    // T1: bijective XCD swizzle over the per-z 2D grid
    int lin = blockIdx.y * gridDim.x + blockIdx.x;
    {
        const int nwg = gridDim.x * gridDim.y;
        const int qq = nwg >> 3, rr = nwg & 7;
        const int xcd = lin & 7, idx = lin >> 3;
        lin = (xcd < rr ? xcd * (qq + 1) : rr * (qq + 1) + (xcd - rr) * qq) + idx;
    }
    const long m0 = (long)(lin / gridDim.x) * 256;
    const long n0 = (long)(lin % gridDim.x) * 256;

    A += (long)blockIdx.z * strA;
    BT += (long)blockIdx.z * strBT;

    const int schunk = (tid & 3) ^ ((tid >> 3) & 3);
    const bf16* pa = A + (m0 + (tid >> 2)) * (long)K + schunk * 8;
    const bf16* pb = BT + (n0 + (tid >> 2)) * (long)K + schunk * 8;
    const long rowK = 128L * (long)K;
    const int stgOff = wv * 512;  // wave-uniform 1 KiB slot

    // fragment read: lane (fm,q) reads row base+fm, chunk q ^ ((fm>>1)&3)
    const int fm = l & 15, q = l >> 4;
    const int lof = fm * 32 + ((q ^ ((fm >> 1) & 3)) * 8);

    f32x4 acc[8][4];
#pragma unroll
    for (int i = 0; i < 8; ++i)
#pragma unroll
        for (int j = 0; j < 4; ++j) acc[i][j] = (f32x4){0.f, 0.f, 0.f, 0.f};

    const int NT = K >> 6;

    // ---- prologue: stage all 4 halves of tile 0 into buf0
    {
        bf16* dA0 = lds + stgOff;
        bf16* dA1 = lds + 8192 + stgOff;
        bf16* dB0 = lds + 32768 + stgOff;
        bf16* dB1 = lds + 40960 + stgOff;
        gl2lds16(pa, dA0);       gl2lds16(pa + rowK, dA0 + 4096);
        gl2lds16(pb, dB0);       gl2lds16(pb + rowK, dB0 + 4096);
        gl2lds16(pa + 32, dA1);  gl2lds16(pa + 32 + rowK, dA1 + 4096);
        gl2lds16(pb + 32, dB1);  gl2lds16(pb + 32 + rowK, dB1 + 4096);
        asm volatile("s_waitcnt vmcnt(4)" ::: "memory");  // s0 done, s1 in flight
        __builtin_amdgcn_s_barrier();
    }

    for (int t = 0; t < NT; ++t) {
        const int buf = t & 1;
        const bool more = (t + 1) < NT;
        const long ko = (long)(t + 1) * 64;
        const bf16* As0 = lds + buf * 16384;
        const bf16* As1 = As0 + 8192;
        const bf16* Bs0 = lds + 32768 + buf * 16384;
        const bf16* Bs1 = Bs0 + 8192;
        bf16* nA0 = lds + (buf ^ 1) * 16384 + stgOff;
        bf16* nA1 = nA0 + 8192;
        bf16* nB0 = lds + 32768 + (buf ^ 1) * 16384 + stgOff;
        bf16* nB1 = nB0 + 8192;

        // ================= half 0 (kslice 0) =================
        {
            const bf16* bb = Bs0 + (wc * 64) * 32 + lof;
            const bf16* ab = As0 + (wr * 128) * 32 + lof;
            bf16x8 bq[4], a0[4], a1[4];
#pragma unroll
            for (int j = 0; j < 4; ++j) bq[j] = *(const bf16x8*)(bb + j * 512);
#pragma unroll
            for (int i = 0; i < 4; ++i) a0[i] = *(const bf16x8*)(ab + i * 512);
#pragma unroll
            for (int i = 0; i < 4; ++i) a1[i] = *(const bf16x8*)(ab + 64 * 32 + i * 512);
            if (more) {
                gl2lds16(pa + ko, nA0); gl2lds16(pa + ko + rowK, nA0 + 4096);   // S_A0
                gl2lds16(pb + ko, nB0); gl2lds16(pb + ko + rowK, nB0 + 4096);   // S_B0
            }
            __builtin_amdgcn_s_setprio(1);
#pragma unroll
            for (int i = 0; i < 4; ++i)
#pragma unroll
                for (int j = 0; j < 4; ++j)
                    acc[i][j] = __builtin_amdgcn_mfma_f32_16x16x32_bf16(a0[i], bq[j], acc[i][j], 0, 0, 0);
            __builtin_amdgcn_s_setprio(0);
            if (more) { gl2lds16(pa + ko + 32, nA1); gl2lds16(pa + ko + 32 + rowK, nA1 + 4096); }  // S_A1
            __builtin_amdgcn_s_setprio(1);
#pragma unroll
            for (int i = 0; i < 4; ++i)
#pragma unroll
                for (int j = 0; j < 4; ++j)
                    acc[4 + i][j] = __builtin_amdgcn_mfma_f32_16x16x32_bf16(a1[i], bq[j], acc[4 + i][j], 0, 0, 0);
            __builtin_amdgcn_s_setprio(0);
        }
        // publish s1(t)
        if (more) asm volatile("s_waitcnt vmcnt(6)" ::: "memory");
        else      asm volatile("s_waitcnt vmcnt(0)" ::: "memory");
        __builtin_amdgcn_s_barrier();

        // ================= half 1 (kslice 1) =================
        {
            const bf16* bb = Bs1 + (wc * 64) * 32 + lof;
            const bf16* ab = As1 + (wr * 128) * 32 + lof;
            bf16x8 bq[4], a0[4], a1[4];
#pragma unroll
            for (int j = 0; j < 4; ++j) bq[j] = *(const bf16x8*)(bb + j * 512);
#pragma unroll
            for (int i = 0; i < 4; ++i) a0[i] = *(const bf16x8*)(ab + i * 512);
#pragma unroll
            for (int i = 0; i < 4; ++i) a1[i] = *(const bf16x8*)(ab + 64 * 32 + i * 512);
            if (more) { gl2lds16(pb + ko + 32, nB1); gl2lds16(pb + ko + 32 + rowK, nB1 + 4096); }  // S_B1
            __builtin_amdgcn_s_setprio(1);
#pragma unroll
            for (int i = 0; i < 4; ++i)
#pragma unroll
                for (int j = 0; j < 4; ++j)
                    acc[i][j] = __builtin_amdgcn_mfma_f32_16x16x32_bf16(a0[i], bq[j], acc[i][j], 0, 0, 0);
            __builtin_amdgcn_s_setprio(0);
            __builtin_amdgcn_s_setprio(1);
#pragma unroll
            for (int i = 0; i < 4; ++i)
#pragma unroll
                for (int j = 0; j < 4; ++j)
                    acc[4 + i][j] = __builtin_amdgcn_mfma_f32_16x16x32_bf16(a1[i], bq[j], acc[4 + i][j], 0, 0, 0);
            __builtin_amdgcn_s_setprio(0);
        }
        // publish s0(t+1)
        if (more) {
            asm volatile("s_waitcnt vmcnt(4)" ::: "memory");
            __builtin_amdgcn_s_barrier();
        }
    }

    // -------- epilogue --------
    const long cb = (long)blockIdx.z * strC;
    float uu[4], tb[4];
    if (EPI == 1) {
#pragma unroll
        for (int j = 0; j < 4; ++j) {
            const long col = n0 + wc * 64 + j * 16 + fm;
            uu[j] = uArr[col];
            tb[j] = tArr[col] + bias[col];
        }
    }
#pragma unroll
    for (int i = 0; i < 8; ++i) {
        const long rB = m0 + wr * 128 + i * 16 + q * 4;
#pragma unroll
        for (int r2 = 0; r2 < 4; ++r2) {
            const long row = rB + r2;
            float2 st;
            if (EPI == 1) st = is2[row];
#pragma unroll
            for (int j = 0; j < 4; ++j) {
                const long col = n0 + wc * 64 + j * 16 + fm;
                float v = acc[i][j][r2];
                if (EPI == 0) {
                    v += bias[row];
                    ((bf16*)Cp)[cb + row * (long)N + col] = __float2bfloat16(v);
                } else if (EPI == 1) {
                    v = st.x * v - st.y * uu[j] + tb[j];
                    v = gelu_exact(v);
                    ((bf16*)Cp)[cb + row * (long)N + col] = __float2bfloat16(v);
                } else {
                    v += bias[col] + Xadd[row * (long)N + col];
                    ((float*)Cp)[cb + row * (long)N + col] = v;
                }
            }
        }
    }
}

// ---------------- fp32 -> bf16 straight convert ----------------
__global__ void conv_bf16(const float* __restrict__ in, bf16* __restrict__ out, long n) {
    long i = ((long)blockIdx.x * 256 + threadIdx.x) * 4;
    if (i >= n) return;
    const float4 v = *(const float4*)(in + i);
    bf16 o[4] = {__float2bfloat16(v.x), __float2bfloat16(v.y),
                 __float2bfloat16(v.z), __float2bfloat16(v.w)};
    *(uint2*)(out + i) = *(uint2*)o;
}

// ---------------- fp32 (R x C) -> bf16 (C x R) transpose, z-batched ----------
// optional per-input-row scale (rscale[r], r in [0,R)) for gamma-folded W1
__global__ void transpose_f32_bf16(const float* __restrict__ in, bf16* __restrict__ out,
                                   int R, int C, long inStr, long outStr,
                                   const float* __restrict__ rscale) {
    __shared__ float tl[64][65];
    const float* ip = in + (long)blockIdx.z * inStr;
    bf16* op = out + (long)blockIdx.z * outStr;
    const int r0 = blockIdx.y * 64, c0 = blockIdx.x * 64;
    const int tr = threadIdx.x >> 6, tc = threadIdx.x & 63;
#pragma unroll
    for (int k = 0; k < 16; k++) {
        int r = k * 4 + tr;
        float v = ip[(long)(r0 + r) * C + c0 + tc];
        if (rscale) v *= rscale[r0 + r];
        tl[r][tc] = v;
    }
    __syncthreads();
#pragma unroll
    for (int k = 0; k < 16; k++) {
        int r = k * 4 + tr;
        op[(long)(c0 + r) * R + r0 + tc] = __float2bfloat16(tl[tc][r]);
    }
}

// ---------------- u/t prep: u[g]=sum_f gamma[f]W1[f,g], t[g]=sum_f beta[f]W1[f,g]
__global__ void zero_f32(float* p, int n) {
    int i = blockIdx.x * 256 + threadIdx.x;
    if (i < n) p[i] = 0.f;
}

__global__ void ut_kernel(const float* __restrict__ W1, const float* __restrict__ gamma,
                          const float* __restrict__ beta, float* __restrict__ uArr,
                          float* __restrict__ tArr) {
    const int g = blockIdx.x * 256 + threadIdx.x;
    const int f0 = blockIdx.y * 512;
    float su = 0.f, st = 0.f;
    for (int f = 0; f < 512; ++f) {
        const float w = W1[(long)(f0 + f) * GDIM + g];
        su += gamma[f0 + f] * w;
        st += beta[f0 + f] * w;
    }
    atomicAdd(&uArr[g], su);
    atomicAdd(&tArr[g], st);
}

// ---------------- scan: phase cumsum + complex memory, writes ctx in (s,f) ----
// 16 waves/block, wave wv scans d = blockIdx.x*16+wv. Per 64-s chunk the
// block stages its 64s x 16d x 4sect bf16 tile in LDS (stride-70 rows,
// conflict-free-ish) then writes 32B-coalesced segments to ctx[s*FD + sect*DD + d].
__global__ __launch_bounds__(1024) void scan16(
    const bf16* __restrict__ omegaT, const bf16* __restrict__ xT,
    const float* __restrict__ log_scale, bf16* __restrict__ ctx,
    long strIn, long strCtx)
{
    __shared__ bf16 stg[64 * 70];
    const int tid = threadIdx.x;
    const int wv = tid >> 6, lane = tid & 63;
    const int d0 = blockIdx.x * 16;
    const int d = d0 + wv;
    const int z = blockIdx.z;
    const float sc = expf(log_scale[d]);
    const bf16* po = omegaT + (long)z * strIn + (long)d * SS;
    const bf16* px = xT + (long)z * strIn + (long)d * SS;
    bf16* pc = ctx + (long)z * strCtx;
    const int so_i = tid >> 4;   // write-phase s index 0..63
    const int so_d = tid & 15;   // write-phase dd 0..15

    float phi_c = 0.f, mr_c = 0.f, mi_c = 0.f;
    for (int tchunk = 0; tchunk < SS / 64; tchunk++) {
        const int s = tchunk * 64 + lane;
        const float pos = (float)(s + 1);
        float w = __bfloat162float(po[s]) * sc * rsqrtf(pos);
#pragma unroll
        for (int dlt = 1; dlt < 64; dlt <<= 1) {
            float v = __shfl_up(w, dlt, 64);
            if (lane >= dlt) w += v;
        }
        const float phi = phi_c + w;
        float sph, cph;
        sincosf(phi, &sph, &cph);
        const float xv = __bfloat162float(px[s]);
        const float cr = xv * cph, ci = xv * sph;
        float crs = cr, cis = ci;
#pragma unroll
        for (int dlt = 1; dlt < 64; dlt <<= 1) {
            float v1 = __shfl_up(crs, dlt, 64);
            float v2 = __shfl_up(cis, dlt, 64);
            if (lane >= dlt) { crs += v1; cis += v2; }
        }
        const float invp = 1.0f / pos;
        const float mr = (mr_c + crs) * invp;
        const float mi = (mi_c + cis) * invp;
        const float rr = mr * cph + mi * sph;
        const float ri = mi * cph - mr * sph;
        // stage (s=lane, dd=wv): row stride 70, sect stride 17
        stg[lane * 70 +      wv] = __float2bfloat16(cr);
        stg[lane * 70 + 17 + wv] = __float2bfloat16(ci);
        stg[lane * 70 + 34 + wv] = __float2bfloat16(rr);
        stg[lane * 70 + 51 + wv] = __float2bfloat16(ri);
        phi_c += __shfl(w, 63, 64);
        mr_c += __shfl(crs, 63, 64);
        mi_c += __shfl(cis, 63, 64);
        __syncthreads();
        // write out: thread (so_i, so_d) -> 4 sections
        bf16* row = pc + (long)(tchunk * 64 + so_i) * FD + d0 + so_d;
        row[0]          = stg[so_i * 70 +      so_d];
        row[DD]         = stg[so_i * 70 + 17 + so_d];
        row[2 * DD]     = stg[so_i * 70 + 34 + so_d];
        row[3 * DD]     = stg[so_i * 70 + 51 + so_d];
        __syncthreads();
    }
}

// ---------------- per-s LN stats from (s,f) ctx: one wave per row -----------
// writes is2[z*SS+s] = (is, is*mu)
__global__ __launch_bounds__(256) void stats2(
    const bf16* __restrict__ ctx, float2* __restrict__ is2, long strCtx)
{
    const int s = blockIdx.x * 4 + (threadIdx.x >> 6);
    const int lane = threadIdx.x & 63;
    const int z = blockIdx.z;
    const bf16* p = ctx + (long)z * strCtx + (long)s * FD;
    float sm = 0.f, sq = 0.f;
#pragma unroll
    for (int i = 0; i < 8; ++i) {
        bf16x8 v8 = *(const bf16x8*)(p + lane * 8 + i * 512);
#pragma unroll
        for (int j = 0; j < 8; ++j) {
            const float v = bf2f((unsigned short)v8[j]);
            sm += v;
            sq += v * v;
        }
    }
#pragma unroll
    for (int o = 1; o < 64; o <<= 1) {
        sm += __shfl_xor(sm, o, 64);
        sq += __shfl_xor(sq, o, 64);
    }
    if (lane == 0) {
        const float mu = sm * (1.0f / FD);
        const float var = sq * (1.0f / FD) - mu * mu;
        const float is = rsqrtf(var + 1e-5f);
        is2[z * SS + s] = make_float2(is, is * mu);
    }
}

// ---------------- launch ----------------
extern "C" void kernel_launch(void* const* d_in, const int* in_sizes, int n_in,
                              void* d_out, int out_size, void* d_ws, size_t ws_size,
                              hipStream_t stream)
{
    const float* x = (const float*)d_in[0];
    const float* Wo = (const float*)d_in[1];
    const float* bo = (const float*)d_in[2];
    const float* lsc = (const float*)d_in[3];
    const float* gam = (const float*)d_in[4];
    const float* bet = (const float*)d_in[5];
    const float* W1 = (const float*)d_in[6];
    const float* b1 = (const float*)d_in[7];
    const float* W2 = (const float*)d_in[8];
    const float* b2 = (const float*)d_in[9];

    static bool attr_done = false;
    if (!attr_done) {
        hipFuncSetAttribute(reinterpret_cast<const void*>(gemm256<0>),
                            hipFuncAttributeMaxDynamicSharedMemorySize, 131072);
        hipFuncSetAttribute(reinterpret_cast<const void*>(gemm256<1>),
                            hipFuncAttributeMaxDynamicSharedMemorySize, 131072);
        hipFuncSetAttribute(reinterpret_cast<const void*>(gemm256<2>),
                            hipFuncAttributeMaxDynamicSharedMemorySize, 131072);
        attr_done = true;
    }

    char* ws = (char*)d_ws;
    const size_t MB = 1024 * 1024;

    bf16* W1gT = (bf16*)(ws + 0);          // 16 MB  (2048 x 4096), gamma-folded
    bf16* W2T = (bf16*)(ws + 16 * MB);     //  4 MB  (1024 x 2048)
    bf16* WoT = (bf16*)(ws + 20 * MB);     //  2 MB  (1024 x 1024)
    float2* is2 = (float2*)(ws + 22 * MB); // 16384 x 8B = 128 KB
    float* uArr = (float*)(ws + 22 * MB + 128 * 1024);   // 8 KB
    float* tArr = (float*)(ws + 22 * MB + 136 * 1024);   // 8 KB

    transpose_f32_bf16<<<dim3(DD / 64, DD / 64, 1), 256, 0, stream>>>(Wo, WoT, DD, DD, 0, 0, nullptr);
    transpose_f32_bf16<<<dim3(GDIM / 64, FD / 64, 1), 256, 0, stream>>>(W1, W1gT, FD, GDIM, 0, 0, gam);
    transpose_f32_bf16<<<dim3(DD / 64, GDIM / 64, 1), 256, 0, stream>>>(W2, W2T, GDIM, DD, 0, 0, nullptr);
    zero_f32<<<(2 * GDIM + 255) / 256, 256, 0, stream>>>(uArr, 2 * GDIM);  // u and t adjacent
    ut_kernel<<<dim3(GDIM / 256, FD / 512, 1), 256, 0, stream>>>(W1, gam, bet, uArr, tArr);

    if (ws_size >= 220 * MB) {
        bf16* xT  = (bf16*)(ws + 23 * MB);
        bf16* omT = (bf16*)(ws + 55 * MB);
        bf16* ctx = (bf16*)(ws + 87 * MB);   // (s,f) per z, 32 MB each
        bf16* xb  = (bf16*)(ws + 87 * MB);   // dead after GEMM1
        bf16* h1  = (bf16*)(ws + 23 * MB);   // overlays xT+omT after scan

        conv_bf16<<<(int)(BB * SD / 1024), 256, 0, stream>>>(x, xb, BB * SD);
        transpose_f32_bf16<<<dim3(DD / 64, SS / 64, BB), 256, 0, stream>>>(x, xT, SS, DD, SD, SD, nullptr);

        // GEMM1 batched: omega^T[b] = Wo^T * x[b]^T   (M=1024, N=4096, K=1024)
        gemm256<0><<<dim3(SS / 256, DD / 256, BB), 512, 131072, stream>>>(
            WoT, xb, omT, bo, nullptr, nullptr, nullptr, nullptr, DD, SS, DD, 0L, SD, SD);

        // phase scan -> ctx in (s,f)
        scan16<<<dim3(DD / 16, 1, BB), 1024, 0, stream>>>(omT, xT, lsc, ctx, SD, SD4);

        // per-row LN stats (is, is*mu)
        stats2<<<dim3(SS / 4, 1, BB), 256, 0, stream>>>(ctx, is2, SD4);

        // GEMM2 (M=16384, N=2048, K=4096): h1 = gelu(LN-folded(ctx) * W1g + ...)
        gemm256<1><<<dim3(GDIM / 256, BB * SS / 256, 1), 512, 131072, stream>>>(
            ctx, W1gT, h1, b1, nullptr, is2, uArr, tArr, BB * SS, GDIM, FD, 0L, 0L, 0L);

        // GEMM3 (M=16384, N=1024, K=2048): out = x + h1 * W2 + b2, fp32
        gemm256<2><<<dim3(DD / 256, BB * SS / 256, 1), 512, 131072, stream>>>(
            h1, W2T, d_out, b2, x, nullptr, nullptr, nullptr, BB * SS, DD, GDIM, 0L, 0L, 0L);
    } else {
        bf16* xb  = (bf16*)(ws + 23 * MB);
        bf16* ctx = (bf16*)(ws + 23 * MB);   // 32 MB (s,f), overlays xb after GEMM1
        bf16* omT = (bf16*)(ws + 55 * MB);
        bf16* xT  = (bf16*)(ws + 63 * MB);
        bf16* h1  = (bf16*)(ws + 55 * MB);

        for (int b = 0; b < BB; b++) {
            const float* xbf = x + (long)b * SD;
            conv_bf16<<<(int)(SD / 1024), 256, 0, stream>>>(xbf, xb, SD);
            transpose_f32_bf16<<<dim3(DD / 64, SS / 64, 1), 256, 0, stream>>>(xbf, xT, SS, DD, 0, 0, nullptr);
            gemm256<0><<<dim3(SS / 256, DD / 256, 1), 512, 131072, stream>>>(
                WoT, xb, omT, bo, nullptr, nullptr, nullptr, nullptr, DD, SS, DD, 0L, 0L, 0L);
            scan16<<<dim3(DD / 16, 1, 1), 1024, 0, stream>>>(omT, xT, lsc, ctx, 0L, 0L);
            stats2<<<dim3(SS / 4, 1, 1), 256, 0, stream>>>(ctx, is2, 0L);
            gemm256<1><<<dim3(GDIM / 256, SS / 256, 1), 512, 131072, stream>>>(
                ctx, W1gT, h1, b1, nullptr, is2, uArr, tArr, SS, GDIM, FD, 0L, 0L, 0L);
            gemm256<2><<<dim3(DD / 256, SS / 256, 1), 512, 131072, stream>>>(
                h1, W2T, (float*)d_out + (long)b * SD, b2, xbf, nullptr, nullptr, nullptr,
                SS, DD, GDIM, 0L, 0L, 0L);
        }
    }
}

// Round 8
// 709.633 us; speedup vs baseline: 1.1197x; 1.0769x over previous
//
#include <hip/hip_runtime.h>
#include <hip/hip_bf16.h>
#include <math.h>

typedef __hip_bfloat16 bf16;
typedef __attribute__((ext_vector_type(8))) short bf16x8;
typedef __attribute__((ext_vector_type(4))) float f32x4;

static constexpr int DD = 1024;    // D
static constexpr int BB = 4;       // batch
static constexpr int SS = 4096;    // seq
static constexpr int FD = 4096;    // 4D
static constexpr int GDIM = 2048;  // 2D
static constexpr long SD = (long)SS * DD;   // per-batch x elements (4M)
static constexpr long SD4 = 4 * SD;         // per-batch ctx elements

// ---------------- async global->LDS (16B per lane) ----------------
__device__ __forceinline__ void gl2lds16(const bf16* g, bf16* l) {
    __builtin_amdgcn_global_load_lds(
        (const __attribute__((address_space(1))) void*)g,
        (__attribute__((address_space(3))) void*)l, 16, 0, 0);
}

// ---------------- branchless exact-erf GELU (A&S 7.1.26, |eps|<=1.5e-7) -----
__device__ __forceinline__ float gelu_exact(float v) {
    const float ax = fabsf(v) * 0.70710678118654752f;  // |v|/sqrt(2)
    const float t = 1.0f / (1.0f + 0.3275911f * ax);
    const float poly = t * (0.254829592f + t * (-0.284496736f +
                       t * (1.421413741f + t * (-1.453152027f + t * 1.061405429f))));
    const float er = 1.0f - poly * __expf(-ax * ax);
    const float erfv = v < 0.f ? -er : er;
    return 0.5f * v * (1.0f + erfv);
}

__device__ __forceinline__ float bf2f(unsigned short us) {
    return __uint_as_float(((unsigned)us) << 16);
}

// ================= 256x256 GEMM, 16x16x32 MFMA, 2 barriers/K-tile ==========
// (verified core: 0 bank conflicts, GEMM2 270us @ MfmaUtil 46.7, round 7)
// EPI 0: +bias[row], bf16
// EPI 1: LN-FOLDED: v = is[s]*acc - (is*mu)[s]*u[col] + t[col] + bias[col];
//        gelu; bf16.  (A = RAW ctx (s,f), B = gamma-scaled W1T)
// EPI 2: +bias[col]+X[row,col], f32
template <int EPI>
__global__ __launch_bounds__(512, 2) void gemm256(
    const bf16* __restrict__ A, const bf16* __restrict__ BT, void* __restrict__ Cp,
    const float* __restrict__ bias, const float* __restrict__ Xadd,
    const float2* __restrict__ is2, const float* __restrict__ uArr,
    const float* __restrict__ tArr,
    int M, int N, int K, long strA, long strBT, long strC)
{
    extern __shared__ bf16 lds[];  // 65536 elems: A [0,32768), B [32768,65536)
    const int tid = threadIdx.x;
    const int l = tid & 63, wv = tid >> 6;
    const int wr = wv >> 2, wc = wv & 3;

    // T1: bijective XCD swizzle over the per-z 2D grid
    int lin = blockIdx.y * gridDim.x + blockIdx.x;
    {
        const int nwg = gridDim.x * gridDim.y;
        const int qq = nwg >> 3, rr = nwg & 7;
        const int xcd = lin & 7, idx = lin >> 3;
        lin = (xcd < rr ? xcd * (qq + 1) : rr * (qq + 1) + (xcd - rr) * qq) + idx;
    }
    const long m0 = (long)(lin / gridDim.x) * 256;
    const long n0 = (long)(lin % gridDim.x) * 256;

    A += (long)blockIdx.z * strA;
    BT += (long)blockIdx.z * strBT;

    const int schunk = (tid & 3) ^ ((tid >> 3) & 3);
    const bf16* pa = A + (m0 + (tid >> 2)) * (long)K + schunk * 8;
    const bf16* pb = BT + (n0 + (tid >> 2)) * (long)K + schunk * 8;
    const long rowK = 128L * (long)K;
    const int stgOff = wv * 512;  // wave-uniform 1 KiB slot

    const int fm = l & 15, q = l >> 4;
    const int lof = fm * 32 + ((q ^ ((fm >> 1) & 3)) * 8);

    f32x4 acc[8][4];
#pragma unroll
    for (int i = 0; i < 8; ++i)
#pragma unroll
        for (int j = 0; j < 4; ++j) acc[i][j] = (f32x4){0.f, 0.f, 0.f, 0.f};

    const int NT = K >> 6;

    // ---- prologue: stage all 4 halves of tile 0 into buf0
    {
        bf16* dA0 = lds + stgOff;
        bf16* dA1 = lds + 8192 + stgOff;
        bf16* dB0 = lds + 32768 + stgOff;
        bf16* dB1 = lds + 40960 + stgOff;
        gl2lds16(pa, dA0);       gl2lds16(pa + rowK, dA0 + 4096);
        gl2lds16(pb, dB0);       gl2lds16(pb + rowK, dB0 + 4096);
        gl2lds16(pa + 32, dA1);  gl2lds16(pa + 32 + rowK, dA1 + 4096);
        gl2lds16(pb + 32, dB1);  gl2lds16(pb + 32 + rowK, dB1 + 4096);
        asm volatile("s_waitcnt vmcnt(4)" ::: "memory");  // s0 done, s1 in flight
        __builtin_amdgcn_s_barrier();
    }

    for (int t = 0; t < NT; ++t) {
        const int buf = t & 1;
        const bool more = (t + 1) < NT;
        const long ko = (long)(t + 1) * 64;
        const bf16* As0 = lds + buf * 16384;
        const bf16* As1 = As0 + 8192;
        const bf16* Bs0 = lds + 32768 + buf * 16384;
        const bf16* Bs1 = Bs0 + 8192;
        bf16* nA0 = lds + (buf ^ 1) * 16384 + stgOff;
        bf16* nA1 = nA0 + 8192;
        bf16* nB0 = lds + 32768 + (buf ^ 1) * 16384 + stgOff;
        bf16* nB1 = nB0 + 8192;

        // ================= half 0 (kslice 0) =================
        {
            const bf16* bb = Bs0 + (wc * 64) * 32 + lof;
            const bf16* ab = As0 + (wr * 128) * 32 + lof;
            bf16x8 bq[4], a0[4], a1[4];
#pragma unroll
            for (int j = 0; j < 4; ++j) bq[j] = *(const bf16x8*)(bb + j * 512);
#pragma unroll
            for (int i = 0; i < 4; ++i) a0[i] = *(const bf16x8*)(ab + i * 512);
#pragma unroll
            for (int i = 0; i < 4; ++i) a1[i] = *(const bf16x8*)(ab + 64 * 32 + i * 512);
            if (more) {
                gl2lds16(pa + ko, nA0); gl2lds16(pa + ko + rowK, nA0 + 4096);   // S_A0
                gl2lds16(pb + ko, nB0); gl2lds16(pb + ko + rowK, nB0 + 4096);   // S_B0
            }
            __builtin_amdgcn_s_setprio(1);
#pragma unroll
            for (int i = 0; i < 4; ++i)
#pragma unroll
                for (int j = 0; j < 4; ++j)
                    acc[i][j] = __builtin_amdgcn_mfma_f32_16x16x32_bf16(a0[i], bq[j], acc[i][j], 0, 0, 0);
            __builtin_amdgcn_s_setprio(0);
            if (more) { gl2lds16(pa + ko + 32, nA1); gl2lds16(pa + ko + 32 + rowK, nA1 + 4096); }  // S_A1
            __builtin_amdgcn_s_setprio(1);
#pragma unroll
            for (int i = 0; i < 4; ++i)
#pragma unroll
                for (int j = 0; j < 4; ++j)
                    acc[4 + i][j] = __builtin_amdgcn_mfma_f32_16x16x32_bf16(a1[i], bq[j], acc[4 + i][j], 0, 0, 0);
            __builtin_amdgcn_s_setprio(0);
        }
        // publish s1(t)
        if (more) asm volatile("s_waitcnt vmcnt(6)" ::: "memory");
        else      asm volatile("s_waitcnt vmcnt(0)" ::: "memory");
        __builtin_amdgcn_s_barrier();

        // ================= half 1 (kslice 1) =================
        {
            const bf16* bb = Bs1 + (wc * 64) * 32 + lof;
            const bf16* ab = As1 + (wr * 128) * 32 + lof;
            bf16x8 bq[4], a0[4], a1[4];
#pragma unroll
            for (int j = 0; j < 4; ++j) bq[j] = *(const bf16x8*)(bb + j * 512);
#pragma unroll
            for (int i = 0; i < 4; ++i) a0[i] = *(const bf16x8*)(ab + i * 512);
#pragma unroll
            for (int i = 0; i < 4; ++i) a1[i] = *(const bf16x8*)(ab + 64 * 32 + i * 512);
            if (more) { gl2lds16(pb + ko + 32, nB1); gl2lds16(pb + ko + 32 + rowK, nB1 + 4096); }  // S_B1
            __builtin_amdgcn_s_setprio(1);
#pragma unroll
            for (int i = 0; i < 4; ++i)
#pragma unroll
                for (int j = 0; j < 4; ++j)
                    acc[i][j] = __builtin_amdgcn_mfma_f32_16x16x32_bf16(a0[i], bq[j], acc[i][j], 0, 0, 0);
            __builtin_amdgcn_s_setprio(0);
            __builtin_amdgcn_s_setprio(1);
#pragma unroll
            for (int i = 0; i < 4; ++i)
#pragma unroll
                for (int j = 0; j < 4; ++j)
                    acc[4 + i][j] = __builtin_amdgcn_mfma_f32_16x16x32_bf16(a1[i], bq[j], acc[4 + i][j], 0, 0, 0);
            __builtin_amdgcn_s_setprio(0);
        }
        // publish s0(t+1)
        if (more) {
            asm volatile("s_waitcnt vmcnt(4)" ::: "memory");
            __builtin_amdgcn_s_barrier();
        }
    }

    // -------- epilogue --------
    const long cb = (long)blockIdx.z * strC;
    float uu[4], tb[4];
    if (EPI == 1) {
#pragma unroll
        for (int j = 0; j < 4; ++j) {
            const long col = n0 + wc * 64 + j * 16 + fm;
            uu[j] = uArr[col];
            tb[j] = tArr[col] + bias[col];
        }
    }
#pragma unroll
    for (int i = 0; i < 8; ++i) {
        const long rB = m0 + wr * 128 + i * 16 + q * 4;
#pragma unroll
        for (int r2 = 0; r2 < 4; ++r2) {
            const long row = rB + r2;
            float2 st;
            if (EPI == 1) st = is2[row];
#pragma unroll
            for (int j = 0; j < 4; ++j) {
                const long col = n0 + wc * 64 + j * 16 + fm;
                float v = acc[i][j][r2];
                if (EPI == 0) {
                    v += bias[row];
                    ((bf16*)Cp)[cb + row * (long)N + col] = __float2bfloat16(v);
                } else if (EPI == 1) {
                    v = st.x * v - st.y * uu[j] + tb[j];
                    v = gelu_exact(v);
                    ((bf16*)Cp)[cb + row * (long)N + col] = __float2bfloat16(v);
                } else {
                    v += bias[col] + Xadd[row * (long)N + col];
                    ((float*)Cp)[cb + row * (long)N + col] = v;
                }
            }
        }
    }
}

// ---------------- fp32 -> bf16 straight convert ----------------
__global__ void conv_bf16(const float* __restrict__ in, bf16* __restrict__ out, long n) {
    long i = ((long)blockIdx.x * 256 + threadIdx.x) * 4;
    if (i >= n) return;
    const float4 v = *(const float4*)(in + i);
    bf16 o[4] = {__float2bfloat16(v.x), __float2bfloat16(v.y),
                 __float2bfloat16(v.z), __float2bfloat16(v.w)};
    *(uint2*)(out + i) = *(uint2*)o;
}

// ---------------- fp32 (R x C) -> bf16 (C x R) transpose, z-batched ----------
// optional per-input-row scale (rscale[r]) for gamma-folded W1
__global__ void transpose_f32_bf16(const float* __restrict__ in, bf16* __restrict__ out,
                                   int R, int C, long inStr, long outStr,
                                   const float* __restrict__ rscale) {
    __shared__ float tl[64][65];
    const float* ip = in + (long)blockIdx.z * inStr;
    bf16* op = out + (long)blockIdx.z * outStr;
    const int r0 = blockIdx.y * 64, c0 = blockIdx.x * 64;
    const int tr = threadIdx.x >> 6, tc = threadIdx.x & 63;
#pragma unroll
    for (int k = 0; k < 16; k++) {
        int r = k * 4 + tr;
        float v = ip[(long)(r0 + r) * C + c0 + tc];
        if (rscale) v *= rscale[r0 + r];
        tl[r][tc] = v;
    }
    __syncthreads();
#pragma unroll
    for (int k = 0; k < 16; k++) {
        int r = k * 4 + tr;
        op[(long)(c0 + r) * R + r0 + tc] = __float2bfloat16(tl[tc][r]);
    }
}

// ---------------- u/t prep ----------------
__global__ void zero_f32(float* p, int n) {
    int i = blockIdx.x * 256 + threadIdx.x;
    if (i < n) p[i] = 0.f;
}

__global__ void ut_kernel(const float* __restrict__ W1, const float* __restrict__ gamma,
                          const float* __restrict__ beta, float* __restrict__ uArr,
                          float* __restrict__ tArr) {
    const int g = blockIdx.x * 256 + threadIdx.x;
    const int f0 = blockIdx.y * 512;
    float su = 0.f, st = 0.f;
    for (int f = 0; f < 512; ++f) {
        const float w = W1[(long)(f0 + f) * GDIM + g];
        su += gamma[f0 + f] * w;
        st += beta[f0 + f] * w;
    }
    atomicAdd(&uArr[g], su);
    atomicAdd(&tArr[g], st);
}

// ---------------- scan8: two-level phase scan, 8 waves per (z,d) column -----
// Wave w owns s in [w*512,(w+1)*512) = 8 chunks of 64. Local scans + LDS
// segment totals + barrier + offset. Serial chain 64 -> ~17 chunk-steps;
// TLP 4 -> 32 waves/CU. Output ctx in (f,s): fully coalesced 128B stores.
__global__ __launch_bounds__(512) void scan8(
    const bf16* __restrict__ omegaT, const bf16* __restrict__ xT,
    const float* __restrict__ log_scale, bf16* __restrict__ ctx,
    long strIn, long strCtx)
{
    __shared__ float stA[8], stB[8], stC[8];
    const int d = blockIdx.x;
    const int z = blockIdx.z;
    const int wv = threadIdx.x >> 6, lane = threadIdx.x & 63;
    const float sc = expf(log_scale[d]);
    const bf16* po = omegaT + (long)z * strIn + (long)d * SS;
    const bf16* px = xT + (long)z * strIn + (long)d * SS;
    bf16* pc = ctx + (long)z * strCtx + (long)d * SS;  // (f,s) layout

    const int s0 = wv * 512;
    float phi_loc[8], xv[8], cph[8], sph[8], crs[8], cis[8];

    // phase 1: local phi scans
    float lphi = 0.f;
#pragma unroll
    for (int c = 0; c < 8; ++c) {
        const int s = s0 + c * 64 + lane;
        const float pos = (float)(s + 1);
        float w = __bfloat162float(po[s]) * sc * rsqrtf(pos);
        xv[c] = __bfloat162float(px[s]);
#pragma unroll
        for (int dlt = 1; dlt < 64; dlt <<= 1) {
            float v = __shfl_up(w, dlt, 64);
            if (lane >= dlt) w += v;
        }
        phi_loc[c] = lphi + w;
        lphi += __shfl(w, 63, 64);
    }
    if (lane == 0) stA[wv] = lphi;
    __syncthreads();
    float phi_off = 0.f;
#pragma unroll
    for (int u = 0; u < 8; ++u) phi_off += (u < wv) ? stA[u] : 0.f;

    // phase 2: sincos + local cr/ci scans
    float lcr = 0.f, lci = 0.f;
#pragma unroll
    for (int c = 0; c < 8; ++c) {
        const float phi = phi_loc[c] + phi_off;
        float sp, cp;
        sincosf(phi, &sp, &cp);
        cph[c] = cp; sph[c] = sp;
        float a = xv[c] * cp, b = xv[c] * sp;
#pragma unroll
        for (int dlt = 1; dlt < 64; dlt <<= 1) {
            float v1 = __shfl_up(a, dlt, 64);
            float v2 = __shfl_up(b, dlt, 64);
            if (lane >= dlt) { a += v1; b += v2; }
        }
        crs[c] = lcr + a;
        cis[c] = lci + b;
        lcr += __shfl(a, 63, 64);
        lci += __shfl(b, 63, 64);
    }
    if (lane == 0) { stB[wv] = lcr; stC[wv] = lci; }
    __syncthreads();
    float roff = 0.f, ioff = 0.f;
#pragma unroll
    for (int u = 0; u < 8; ++u) {
        roff += (u < wv) ? stB[u] : 0.f;
        ioff += (u < wv) ? stC[u] : 0.f;
    }

    // phase 3: outputs (coalesced 128B per store)
#pragma unroll
    for (int c = 0; c < 8; ++c) {
        const int s = s0 + c * 64 + lane;
        const float invp = 1.0f / (float)(s + 1);
        const float mr = (crs[c] + roff) * invp;
        const float mi = (cis[c] + ioff) * invp;
        const float cp = cph[c], sp = sph[c];
        const float cr = xv[c] * cp, ci = xv[c] * sp;
        const float rr = mr * cp + mi * sp;
        const float ri = mi * cp - mr * sp;
        pc[s] = __float2bfloat16(cr);
        pc[(long)DD * SS + s] = __float2bfloat16(ci);
        pc[2L * DD * SS + s] = __float2bfloat16(rr);
        pc[3L * DD * SS + s] = __float2bfloat16(ri);
    }
}

// ---------------- in-place (f,s)->(s,f) transpose, triangular tile pairs ----
// per z: ctx is a 4096x4096 bf16 square (FD == SS). lnt_pair structure
// (proven 7 rounds) minus the LN math.
__global__ __launch_bounds__(256) void tpair(bf16* __restrict__ ctx, long strCtx) {
    __shared__ float tA[64][65];
    __shared__ float tB[64][65];
    const int z = blockIdx.z;
    int rem = blockIdx.x, a = 0;
    for (int i = 0; i < 64; i++) {
        int cnt = 64 - i;
        if (rem < cnt) { a = i; break; }
        rem -= cnt;
    }
    const int b = a + rem;
    bf16* base = ctx + (long)z * strCtx;
    const int tr = threadIdx.x >> 6, tc = threadIdx.x & 63;
#pragma unroll
    for (int k = 0; k < 16; k++) {
        int i = k * 4 + tr;
        tA[i][tc] = __bfloat162float(base[(long)(a * 64 + i) * 4096 + b * 64 + tc]);
    }
    if (a != b) {
#pragma unroll
        for (int k = 0; k < 16; k++) {
            int i = k * 4 + tr;
            tB[i][tc] = __bfloat162float(base[(long)(b * 64 + i) * 4096 + a * 64 + tc]);
        }
    }
    __syncthreads();
#pragma unroll
    for (int k = 0; k < 16; k++) {
        int i = k * 4 + tr;
        base[(long)(b * 64 + i) * 4096 + a * 64 + tc] = __float2bfloat16(tA[tc][i]);
    }
    if (a != b) {
#pragma unroll
        for (int k = 0; k < 16; k++) {
            int i = k * 4 + tr;
            base[(long)(a * 64 + i) * 4096 + b * 64 + tc] = __float2bfloat16(tB[tc][i]);
        }
    }
}

// ---------------- per-s LN stats from (s,f) ctx: one wave per row -----------
__global__ __launch_bounds__(256) void stats2(
    const bf16* __restrict__ ctx, float2* __restrict__ is2, long strCtx)
{
    const int s = blockIdx.x * 4 + (threadIdx.x >> 6);
    const int lane = threadIdx.x & 63;
    const int z = blockIdx.z;
    const bf16* p = ctx + (long)z * strCtx + (long)s * FD;
    float sm = 0.f, sq = 0.f;
#pragma unroll
    for (int i = 0; i < 8; ++i) {
        bf16x8 v8 = *(const bf16x8*)(p + lane * 8 + i * 512);
#pragma unroll
        for (int j = 0; j < 8; ++j) {
            const float v = bf2f((unsigned short)v8[j]);
            sm += v;
            sq += v * v;
        }
    }
#pragma unroll
    for (int o = 1; o < 64; o <<= 1) {
        sm += __shfl_xor(sm, o, 64);
        sq += __shfl_xor(sq, o, 64);
    }
    if (lane == 0) {
        const float mu = sm * (1.0f / FD);
        const float var = sq * (1.0f / FD) - mu * mu;
        const float is = rsqrtf(var + 1e-5f);
        is2[z * SS + s] = make_float2(is, is * mu);
    }
}

// ---------------- launch ----------------
extern "C" void kernel_launch(void* const* d_in, const int* in_sizes, int n_in,
                              void* d_out, int out_size, void* d_ws, size_t ws_size,
                              hipStream_t stream)
{
    const float* x = (const float*)d_in[0];
    const float* Wo = (const float*)d_in[1];
    const float* bo = (const float*)d_in[2];
    const float* lsc = (const float*)d_in[3];
    const float* gam = (const float*)d_in[4];
    const float* bet = (const float*)d_in[5];
    const float* W1 = (const float*)d_in[6];
    const float* b1 = (const float*)d_in[7];
    const float* W2 = (const float*)d_in[8];
    const float* b2 = (const float*)d_in[9];

    static bool attr_done = false;
    if (!attr_done) {
        hipFuncSetAttribute(reinterpret_cast<const void*>(gemm256<0>),
                            hipFuncAttributeMaxDynamicSharedMemorySize, 131072);
        hipFuncSetAttribute(reinterpret_cast<const void*>(gemm256<1>),
                            hipFuncAttributeMaxDynamicSharedMemorySize, 131072);
        hipFuncSetAttribute(reinterpret_cast<const void*>(gemm256<2>),
                            hipFuncAttributeMaxDynamicSharedMemorySize, 131072);
        attr_done = true;
    }

    char* ws = (char*)d_ws;
    const size_t MB = 1024 * 1024;

    bf16* W1gT = (bf16*)(ws + 0);          // 16 MB  (2048 x 4096), gamma-folded
    bf16* W2T = (bf16*)(ws + 16 * MB);     //  4 MB  (1024 x 2048)
    bf16* WoT = (bf16*)(ws + 20 * MB);     //  2 MB  (1024 x 1024)
    float2* is2 = (float2*)(ws + 22 * MB); // 128 KB
    float* uArr = (float*)(ws + 22 * MB + 128 * 1024);   // 8 KB
    float* tArr = (float*)(ws + 22 * MB + 136 * 1024);   // 8 KB

    transpose_f32_bf16<<<dim3(DD / 64, DD / 64, 1), 256, 0, stream>>>(Wo, WoT, DD, DD, 0, 0, nullptr);
    transpose_f32_bf16<<<dim3(GDIM / 64, FD / 64, 1), 256, 0, stream>>>(W1, W1gT, FD, GDIM, 0, 0, gam);
    transpose_f32_bf16<<<dim3(DD / 64, GDIM / 64, 1), 256, 0, stream>>>(W2, W2T, GDIM, DD, 0, 0, nullptr);
    zero_f32<<<(2 * GDIM + 255) / 256, 256, 0, stream>>>(uArr, 2 * GDIM);  // u and t adjacent
    ut_kernel<<<dim3(GDIM / 256, FD / 512, 1), 256, 0, stream>>>(W1, gam, bet, uArr, tArr);

    const int NPAIR = 64 * 65 / 2;

    if (ws_size >= 220 * MB) {
        bf16* xT  = (bf16*)(ws + 23 * MB);
        bf16* omT = (bf16*)(ws + 55 * MB);
        bf16* ctx = (bf16*)(ws + 87 * MB);   // 128 MB; (f,s) then in-place (s,f)
        bf16* xb  = (bf16*)(ws + 87 * MB);   // dead after GEMM1
        bf16* h1  = (bf16*)(ws + 23 * MB);   // overlays xT+omT after scan

        conv_bf16<<<(int)(BB * SD / 1024), 256, 0, stream>>>(x, xb, BB * SD);
        transpose_f32_bf16<<<dim3(DD / 64, SS / 64, BB), 256, 0, stream>>>(x, xT, SS, DD, SD, SD, nullptr);

        // GEMM1 batched: omega^T[b] = Wo^T * x[b]^T   (M=1024, N=4096, K=1024)
        gemm256<0><<<dim3(SS / 256, DD / 256, BB), 512, 131072, stream>>>(
            WoT, xb, omT, bo, nullptr, nullptr, nullptr, nullptr, DD, SS, DD, 0L, SD, SD);

        // two-level phase scan -> ctx (f,s)
        scan8<<<dim3(DD, 1, BB), 512, 0, stream>>>(omT, xT, lsc, ctx, SD, SD4);

        // in-place (f,s)->(s,f)
        tpair<<<dim3(NPAIR, 1, BB), 256, 0, stream>>>(ctx, SD4);

        // per-row LN stats (is, is*mu)
        stats2<<<dim3(SS / 4, 1, BB), 256, 0, stream>>>(ctx, is2, SD4);

        // GEMM2 (M=16384, N=2048, K=4096): h1 = gelu(LN-folded(ctx) * W1g + ...)
        gemm256<1><<<dim3(GDIM / 256, BB * SS / 256, 1), 512, 131072, stream>>>(
            ctx, W1gT, h1, b1, nullptr, is2, uArr, tArr, BB * SS, GDIM, FD, 0L, 0L, 0L);

        // GEMM3 (M=16384, N=1024, K=2048): out = x + h1 * W2 + b2, fp32
        gemm256<2><<<dim3(DD / 256, BB * SS / 256, 1), 512, 131072, stream>>>(
            h1, W2T, d_out, b2, x, nullptr, nullptr, nullptr, BB * SS, DD, GDIM, 0L, 0L, 0L);
    } else {
        bf16* xb  = (bf16*)(ws + 23 * MB);
        bf16* ctx = (bf16*)(ws + 23 * MB);   // 32 MB, overlays xb after GEMM1
        bf16* omT = (bf16*)(ws + 55 * MB);
        bf16* xT  = (bf16*)(ws + 63 * MB);
        bf16* h1  = (bf16*)(ws + 55 * MB);

        for (int b = 0; b < BB; b++) {
            const float* xbf = x + (long)b * SD;
            conv_bf16<<<(int)(SD / 1024), 256, 0, stream>>>(xbf, xb, SD);
            transpose_f32_bf16<<<dim3(DD / 64, SS / 64, 1), 256, 0, stream>>>(xbf, xT, SS, DD, 0, 0, nullptr);
            gemm256<0><<<dim3(SS / 256, DD / 256, 1), 512, 131072, stream>>>(
                WoT, xb, omT, bo, nullptr, nullptr, nullptr, nullptr, DD, SS, DD, 0L, 0L, 0L);
            scan8<<<dim3(DD, 1, 1), 512, 0, stream>>>(omT, xT, lsc, ctx, 0L, 0L);
            tpair<<<dim3(NPAIR, 1, 1), 256, 0, stream>>>(ctx, 0L);
            stats2<<<dim3(SS / 4, 1, 1), 256, 0, stream>>>(ctx, is2, 0L);
            gemm256<1><<<dim3(GDIM / 256, SS / 256, 1), 512, 131072, stream>>>(
                ctx, W1gT, h1, b1, nullptr, is2, uArr, tArr, SS, GDIM, FD, 0L, 0L, 0L);
            gemm256<2><<<dim3(DD / 256, SS / 256, 1), 512, 131072, stream>>>(
                h1, W2T, (float*)d_out + (long)b * SD, b2, xbf, nullptr, nullptr, nullptr,
                SS, DD, GDIM, 0L, 0L, 0L);
        }
    }
}